// Round 1
// baseline (785.470 us; speedup 1.0000x reference)
//
#include <hip/hip_runtime.h>
#include <hip/hip_bf16.h>

// Problem constants
static constexpr int NN  = 768;   // N
static constexpr int CSc = 384;   // CS
static constexpr int Hc  = 12;
static constexpr int Cc  = 64;

// -------- workspace layout (float units) --------
static constexpr size_t OFF_ISA    = 0;          // 1024 ints
static constexpr size_t OFF_WCAT   = 1024;       // 128*44
static constexpr size_t OFF_QR     = 8192;                         // 768*768
static constexpr size_t OFF_KVR    = OFF_QR    + 589824;           // 768*1536
static constexpr size_t OFF_QP     = OFF_KVR   + 1179648;          // 768*144
static constexpr size_t OFF_KVP    = OFF_QP    + 110592;           // 768*432
static constexpr size_t OFF_QA     = OFF_KVP   + 331776;           // 768*768
static constexpr size_t OFF_KVA    = OFF_QA    + 589824;           // 768*1536
static constexpr size_t OFF_QPA    = OFF_KVA   + 1179648;          // 768*144
static constexpr size_t OFF_KVPA   = OFF_QPA   + 110592;           // 768*432
static constexpr size_t OFF_Q      = OFF_KVPA  + 331776;           // 768*768
static constexpr size_t OFF_K      = OFF_Q     + 589824;
static constexpr size_t OFF_V      = OFF_K     + 589824;
static constexpr size_t OFF_QPTS   = OFF_V     + 589824;           // 768*144
static constexpr size_t OFF_KPTS   = OFF_QPTS  + 110592;
static constexpr size_t OFF_VPTS   = OFF_KPTS  + 110592;           // 768*288
static constexpr size_t OFF_A      = OFF_VPTS  + 221184;           // 12*768*768 f32
static constexpr size_t OFF_PZ     = OFF_A     + 7077888;          // 768*768*32 bf16 (9437184 f32 slots)
static constexpr size_t OFF_O      = OFF_PZ    + 9437184;          // 768*768
static constexpr size_t OFF_OPTRAW = OFF_O     + 589824;           // 768*288
static constexpr size_t OFF_OPAIR  = OFF_OPTRAW+ 221184;           // 768*384
static constexpr size_t OFF_RESF   = OFF_OPAIR + 294912;           // 768*1536
static constexpr size_t OFF_ATOMF  = OFF_RESF  + 1179648;          // 768*1248
static constexpr size_t OFF_RESOUT = OFF_ATOMF + 958464;           // 768*384
static constexpr size_t OFF_ATOMSC = OFF_RESOUT+ 294912;           // 768*192
static constexpr size_t OFF_ATOMVEC= OFF_ATOMSC+ 147456;           // 768*192

// ---------------- is_atom dtype detection ----------------
// bool(1B) / int32 / float32 all possible; disambiguate from first 768 bytes
// (safe to read under every interpretation).
__global__ void detect_isa(const unsigned int* __restrict__ u, int* __restrict__ ISA) {
  __shared__ int notint;   // set if any of first 192 u32 > 1  -> not int32 0/1
  __shared__ int notfloat; // set if any not in {0, 0x3F800000} -> not float 0/1
  const int t = threadIdx.x;
  if (t == 0) { notint = 0; notfloat = 0; }
  __syncthreads();
  if (t < 192) {
    unsigned v = u[t];
    if (v > 1u) atomicOr(&notint, 1);
    if (v != 0u && v != 0x3F800000u) atomicOr(&notfloat, 1);
  }
  __syncthreads();
  const int mode = (!notint) ? 0 : ((!notfloat) ? 1 : 2); // 0=i32,1=f32,2=byte
  for (int n = t; n < NN; n += 256) {
    int val;
    if (mode == 2) val = (((const unsigned char*)u)[n] != 0);
    else           val = (u[n] != 0u);
    ISA[n] = val;
  }
}

__global__ void build_wcat(const float* __restrict__ wb, const float* __restrict__ wdz,
                           float* __restrict__ W) {
  int idx = blockIdx.x * 256 + threadIdx.x;
  if (idx < 128 * 44) {
    int i = idx / 44, o = idx % 44;
    W[idx] = (o < 12) ? wb[i * 12 + o] : wdz[i * 32 + (o - 12)];
  }
}

// ---------------- generic fp32 GEMM: C = A@B (+bias) ----------------
// 64x64 tile, K-step 16, 256 threads, 4x4 per thread.
__global__ __launch_bounds__(256) void gemm_f32(
    const float* __restrict__ A, int lda,
    const float* __restrict__ B, int ldb,
    const float* __restrict__ bias,
    float* __restrict__ C, int ldc,
    int M, int Nc, int K)
{
  __shared__ __align__(16) float As[16][68];
  __shared__ __align__(16) float Bs[16][68];
  const int bn = blockIdx.x * 64;
  const int bm = blockIdx.y * 64;
  const int t  = threadIdx.x;
  const int tx = t & 15, ty = t >> 4;
  const int arow = t >> 2, akk = (t & 3) << 2;
  const int bkk  = t >> 4, bc  = (t & 15) << 2;
  float acc[4][4] = {};
  for (int k0 = 0; k0 < K; k0 += 16) {
    float4 av = *reinterpret_cast<const float4*>(&A[(size_t)(bm + arow) * lda + k0 + akk]);
    As[akk + 0][arow] = av.x;
    As[akk + 1][arow] = av.y;
    As[akk + 2][arow] = av.z;
    As[akk + 3][arow] = av.w;
    float4 bv = make_float4(0.f, 0.f, 0.f, 0.f);
    if (bn + bc < Nc)
      bv = *reinterpret_cast<const float4*>(&B[(size_t)(k0 + bkk) * ldb + bn + bc]);
    *reinterpret_cast<float4*>(&Bs[bkk][bc]) = bv;
    __syncthreads();
#pragma unroll
    for (int kk = 0; kk < 16; ++kk) {
      float4 a4 = *reinterpret_cast<const float4*>(&As[kk][ty << 2]);
      float4 b4 = *reinterpret_cast<const float4*>(&Bs[kk][tx << 2]);
      float ar[4] = {a4.x, a4.y, a4.z, a4.w};
      float br[4] = {b4.x, b4.y, b4.z, b4.w};
#pragma unroll
      for (int i = 0; i < 4; ++i)
#pragma unroll
        for (int j = 0; j < 4; ++j) acc[i][j] += ar[i] * br[j];
    }
    __syncthreads();
  }
#pragma unroll
  for (int i = 0; i < 4; ++i) {
    int r = bm + (ty << 2) + i;
#pragma unroll
    for (int j = 0; j < 4; ++j) {
      int c = bn + (tx << 2) + j;
      if (r < M && c < Nc)
        C[(size_t)r * ldc + c] = acc[i][j] + (bias ? bias[c] : 0.f);
    }
  }
}

// ---------------- fused z pass: A[h][n][m] = sqrt(1/3)*(z@wb+bb), PZ = bf16(z@wdz+bdz) ----
__global__ __launch_bounds__(256) void zpass_gemm(
    const float* __restrict__ Z, const float* __restrict__ W,
    const float* __restrict__ bb, const float* __restrict__ bdz,
    float* __restrict__ Abuf, __hip_bfloat16* __restrict__ PZ)
{
  __shared__ __align__(16) float As[16][68];
  __shared__ __align__(16) float Bs[16][68];
  const int bm = blockIdx.x * 64;   // row = n*768+m ; 64 | 768 so one n per block
  const int t  = threadIdx.x;
  const int tx = t & 15, ty = t >> 4;
  const int arow = t >> 2, akk = (t & 3) << 2;
  const int bkk  = t >> 4, bc  = (t & 15) << 2;
  float acc[4][4] = {};
  for (int k0 = 0; k0 < 128; k0 += 16) {
    float4 av = *reinterpret_cast<const float4*>(&Z[(size_t)(bm + arow) * 128 + k0 + akk]);
    As[akk + 0][arow] = av.x;
    As[akk + 1][arow] = av.y;
    As[akk + 2][arow] = av.z;
    As[akk + 3][arow] = av.w;
    float4 bv = make_float4(0.f, 0.f, 0.f, 0.f);
    if (bc < 44)
      bv = *reinterpret_cast<const float4*>(&W[(size_t)(k0 + bkk) * 44 + bc]);
    *reinterpret_cast<float4*>(&Bs[bkk][bc]) = bv;
    __syncthreads();
#pragma unroll
    for (int kk = 0; kk < 16; ++kk) {
      float4 a4 = *reinterpret_cast<const float4*>(&As[kk][ty << 2]);
      float4 b4 = *reinterpret_cast<const float4*>(&Bs[kk][tx << 2]);
      float ar[4] = {a4.x, a4.y, a4.z, a4.w};
      float br[4] = {b4.x, b4.y, b4.z, b4.w};
#pragma unroll
      for (int i = 0; i < 4; ++i)
#pragma unroll
        for (int j = 0; j < 4; ++j) acc[i][j] += ar[i] * br[j];
    }
    __syncthreads();
  }
  const float rs3 = 0.5773502691896258f;
#pragma unroll
  for (int i = 0; i < 4; ++i) {
    int row = bm + (ty << 2) + i;
    int n = row / NN;
    int m = row - n * NN;
#pragma unroll
    for (int j = 0; j < 4; ++j) {
      int o = (tx << 2) + j;
      if (o < 12)
        Abuf[((size_t)o * NN + n) * NN + m] = rs3 * (acc[i][j] + bb[o]);
      else if (o < 44)
        PZ[(size_t)row * 32 + (o - 12)] = __float2bfloat16(acc[i][j] + bdz[o - 12]);
    }
  }
}

// ---------------- atom-path point projections from vec ----------------
__global__ void vec_proj(
    const float* __restrict__ s, const float* __restrict__ tfnq_wv,
    const float* __restrict__ tfnkv_wv, const float* __restrict__ trans,
    float* __restrict__ QPA, float* __restrict__ KVPA)
{
  const int n = blockIdx.x;
  const int t = threadIdx.x; // 192
  __shared__ float sv[192];
  sv[t] = s[(size_t)n * CSc + 192 + t];
  __syncthreads();
  if (t < 144) {
    int o = t / 3, x = t % 3;
    float a = 0.f;
    for (int i = 0; i < 64; ++i) a += sv[i * 3 + x] * tfnq_wv[i * 48 + o];
    QPA[(size_t)n * 144 + t] = a + trans[n * 3 + x];
  }
  for (int idx = t; idx < 432; idx += 192) {
    int o = idx / 3, x = idx % 3;
    float a = 0.f;
    for (int i = 0; i < 64; ++i) a += sv[i * 3 + x] * tfnkv_wv[i * 144 + o];
    KVPA[(size_t)n * 432 + idx] = a + trans[n * 3 + x];
  }
}

// ---------------- rigid transform + residue/atom selection ----------------
__global__ void rigid_select(
    const float* __restrict__ QR, const float* __restrict__ KVR,
    const float* __restrict__ QP, const float* __restrict__ KVP,
    const float* __restrict__ QA, const float* __restrict__ KVA,
    const float* __restrict__ QPA, const float* __restrict__ KVPA,
    const float* __restrict__ rot, const float* __restrict__ trans,
    const int* __restrict__ ISA,
    float* __restrict__ Q, float* __restrict__ Kb, float* __restrict__ V,
    float* __restrict__ QPTS, float* __restrict__ KPTS, float* __restrict__ VPTS)
{
  const int n = blockIdx.x;
  const int t = threadIdx.x; // 256
  const bool isa = ISA[n] != 0;
  __shared__ float R[9], T[3];
  if (t < 9) R[t] = rot[(size_t)n * 9 + t];
  if (t < 3) T[t] = trans[(size_t)n * 3 + t];
  __syncthreads();
  for (int idx = t; idx < 768; idx += 256) {
    int h = idx >> 6, c = idx & 63;
    Q[(size_t)n * 768 + idx] = isa ? QA[(size_t)n * 768 + idx] : QR[(size_t)n * 768 + idx];
    Kb[(size_t)n * 768 + idx] = isa ? KVA[(size_t)n * 1536 + h * 128 + c]
                                    : KVR[(size_t)n * 1536 + h * 128 + c];
    V[(size_t)n * 768 + idx]  = isa ? KVA[(size_t)n * 1536 + h * 128 + 64 + c]
                                    : KVR[(size_t)n * 1536 + h * 128 + 64 + c];
  }
  for (int idx = t; idx < 144; idx += 256) {
    int hp = idx / 3, i = idx % 3;
    float val;
    if (isa) val = QPA[(size_t)n * 144 + idx];
    else
      val = R[i * 3 + 0] * QP[(size_t)n * 144 + 0 * 48 + hp] +
            R[i * 3 + 1] * QP[(size_t)n * 144 + 1 * 48 + hp] +
            R[i * 3 + 2] * QP[(size_t)n * 144 + 2 * 48 + hp] + T[i];
    QPTS[(size_t)n * 144 + idx] = val;
  }
  for (int idx = t; idx < 432; idx += 256) {
    int hp = idx / 3, i = idx % 3;   // hp = h*12+pp
    float val;
    if (isa) val = KVPA[(size_t)n * 432 + idx];
    else
      val = R[i * 3 + 0] * KVP[(size_t)n * 432 + 0 * 144 + hp] +
            R[i * 3 + 1] * KVP[(size_t)n * 432 + 1 * 144 + hp] +
            R[i * 3 + 2] * KVP[(size_t)n * 432 + 2 * 144 + hp] + T[i];
    int h = hp / 12, pp = hp % 12;
    if (pp < 4) KPTS[(size_t)n * 144 + (h * 4 + pp) * 3 + i] = val;
    else        VPTS[(size_t)n * 288 + (h * 8 + (pp - 4)) * 3 + i] = val;
  }
}

// ---------------- attention logits: A += sq*q.k + pt_att + mask_pen ----------------
__global__ __launch_bounds__(256) void logits_k(
    const float* __restrict__ Q, const float* __restrict__ Kmat,
    const float* __restrict__ QPTS, const float* __restrict__ KPTS,
    const float* __restrict__ mask, const float* __restrict__ head_w,
    float* __restrict__ Abuf)
{
  const int h  = blockIdx.z;
  const int bn = blockIdx.y * 64;
  const int bm = blockIdx.x * 64;
  const int t  = threadIdx.x;
  const int tx = t & 15, ty = t >> 4;
  const int arow = t >> 2, akk = (t & 3) << 2;
  __shared__ __align__(16) float Ql[16][68], Kl[16][68];
  __shared__ float QPl[64][13], KPl[64][13];
  __shared__ float mskn[64], mskm[64];
  for (int idx = t; idx < 768; idx += 256) {
    int row = idx / 12, d = idx % 12;
    QPl[row][d] = QPTS[(size_t)(bn + row) * 144 + h * 12 + d];
    KPl[row][d] = KPTS[(size_t)(bm + row) * 144 + h * 12 + d];
  }
  if (t < 64) { mskn[t] = mask[bn + t]; mskm[t] = mask[bm + t]; }
  float acc[4][4] = {};
  for (int k0 = 0; k0 < 64; k0 += 16) {
    float4 qv = *reinterpret_cast<const float4*>(&Q[((size_t)(bn + arow) * 12 + h) * 64 + k0 + akk]);
    Ql[akk + 0][arow] = qv.x; Ql[akk + 1][arow] = qv.y;
    Ql[akk + 2][arow] = qv.z; Ql[akk + 3][arow] = qv.w;
    float4 kv = *reinterpret_cast<const float4*>(&Kmat[((size_t)(bm + arow) * 12 + h) * 64 + k0 + akk]);
    Kl[akk + 0][arow] = kv.x; Kl[akk + 1][arow] = kv.y;
    Kl[akk + 2][arow] = kv.z; Kl[akk + 3][arow] = kv.w;
    __syncthreads();
#pragma unroll
    for (int kk = 0; kk < 16; ++kk) {
      float4 a4 = *reinterpret_cast<const float4*>(&Ql[kk][ty << 2]);
      float4 b4 = *reinterpret_cast<const float4*>(&Kl[kk][tx << 2]);
      float ar[4] = {a4.x, a4.y, a4.z, a4.w};
      float br[4] = {b4.x, b4.y, b4.z, b4.w};
#pragma unroll
      for (int i = 0; i < 4; ++i)
#pragma unroll
        for (int j = 0; j < 4; ++j) acc[i][j] += ar[i] * br[j];
    }
    __syncthreads();
  }
  const float hw = log1pf(__expf(head_w[h])) * 0.1360827634879543f; // softplus * sqrt(1/54)
  const float sq = 0.07216878364870322f;                            // sqrt(1/192)
#pragma unroll
  for (int i = 0; i < 4; ++i) {
    int nn = (ty << 2) + i;
#pragma unroll
    for (int j = 0; j < 4; ++j) {
      int mm = (tx << 2) + j;
      float pt = 0.f;
#pragma unroll
      for (int d = 0; d < 12; ++d) {
        float dd = QPl[nn][d] - KPl[mm][d];
        pt += dd * dd;
      }
      float pen = 100000.0f * (mskn[nn] * mskm[mm] - 1.0f);
      size_t idx = ((size_t)h * NN + bn + nn) * NN + bm + mm;
      Abuf[idx] += sq * acc[i][j] - 0.5f * hw * pt + pen;
    }
  }
}

// ---------------- row softmax over m ----------------
__global__ __launch_bounds__(256) void softmax_k(float* __restrict__ Abuf) {
  float* row = Abuf + (size_t)blockIdx.x * NN;
  const int t = threadIdx.x;
  float v0 = row[t], v1 = row[t + 256], v2 = row[t + 512];
  float mx = fmaxf(v0, fmaxf(v1, v2));
#pragma unroll
  for (int off = 32; off > 0; off >>= 1) mx = fmaxf(mx, __shfl_xor(mx, off, 64));
  __shared__ float red[4], red2[4];
  const int wid = t >> 6, lane = t & 63;
  if (lane == 0) red[wid] = mx;
  __syncthreads();
  mx = fmaxf(fmaxf(red[0], red[1]), fmaxf(red[2], red[3]));
  float e0 = __expf(v0 - mx), e1 = __expf(v1 - mx), e2 = __expf(v2 - mx);
  float sm = e0 + e1 + e2;
#pragma unroll
  for (int off = 32; off > 0; off >>= 1) sm += __shfl_xor(sm, off, 64);
  if (lane == 0) red2[wid] = sm;
  __syncthreads();
  sm = red2[0] + red2[1] + red2[2] + red2[3];
  float inv = 1.0f / sm;
  row[t] = e0 * inv; row[t + 256] = e1 * inv; row[t + 512] = e2 * inv;
}

// ---------------- o and o_pt accumulation ----------------
__global__ __launch_bounds__(256) void attn_ov(
    const float* __restrict__ Abuf, const float* __restrict__ V,
    const float* __restrict__ VPTS,
    float* __restrict__ O, float* __restrict__ OPTRAW)
{
  const int h  = blockIdx.y;
  const int bn = blockIdx.x * 32;
  const int t  = threadIdx.x;
  const int nl = t & 31;
  const int g  = t >> 5;   // 8 groups x 11 outs = 88 (64 o + 24 o_pt)
  __shared__ __align__(16) float al[32][68];
  __shared__ __align__(16) float vl[64][92];
  float acc[11] = {};
  for (int m0 = 0; m0 < NN; m0 += 64) {
    for (int i4 = t; i4 < 512; i4 += 256) {
      int row = i4 >> 4, kk = (i4 & 15) << 2;
      *reinterpret_cast<float4*>(&al[row][kk]) =
          *reinterpret_cast<const float4*>(&Abuf[((size_t)h * NN + bn + row) * NN + m0 + kk]);
    }
    for (int i4 = t; i4 < 1024; i4 += 256) {
      int row = i4 >> 4, kk = (i4 & 15) << 2;
      *reinterpret_cast<float4*>(&vl[row][kk]) =
          *reinterpret_cast<const float4*>(&V[((size_t)(m0 + row) * 12 + h) * 64 + kk]);
    }
    for (int i4 = t; i4 < 384; i4 += 256) {
      int row = i4 / 6, kk = (i4 % 6) << 2;
      *reinterpret_cast<float4*>(&vl[row][64 + kk]) =
          *reinterpret_cast<const float4*>(&VPTS[(size_t)(m0 + row) * 288 + h * 24 + kk]);
    }
    __syncthreads();
    for (int mm = 0; mm < 64; ++mm) {
      float av = al[nl][mm];
#pragma unroll
      for (int j = 0; j < 11; ++j) acc[j] += av * vl[mm][g * 11 + j];
    }
    __syncthreads();
  }
  const int n = bn + nl;
#pragma unroll
  for (int j = 0; j < 11; ++j) {
    int o = g * 11 + j;
    if (o < 64) O[(size_t)n * 768 + h * 64 + o] = acc[j];
    else        OPTRAW[(size_t)n * 288 + h * 24 + (o - 64)] = acc[j];
  }
}

// ---------------- o_pair accumulation ----------------
__global__ __launch_bounds__(384) void attn_pair(
    const float* __restrict__ Abuf, const __hip_bfloat16* __restrict__ PZ,
    float* __restrict__ OPAIR)
{
  const int n = blockIdx.x;
  const int t = threadIdx.x; // 384: h = t/32, zc = t%32
  __shared__ __align__(16) float al[12][132];
  __shared__ __align__(16) __hip_bfloat16 pzl[128][32];
  const int h = t >> 5, zc = t & 31;
  float acc = 0.f;
  for (int m0 = 0; m0 < NN; m0 += 128) {
    {
      int hh = t >> 5, kk = (t & 31) << 2;
      *reinterpret_cast<float4*>(&al[hh][kk]) =
          *reinterpret_cast<const float4*>(&Abuf[((size_t)hh * NN + n) * NN + m0 + kk]);
    }
    const uint4* src = reinterpret_cast<const uint4*>(PZ + ((size_t)n * NN + m0) * 32);
    uint4* dst = reinterpret_cast<uint4*>(&pzl[0][0]);
    for (int i4 = t; i4 < 512; i4 += 384) dst[i4] = src[i4];
    __syncthreads();
    for (int mm = 0; mm < 128; ++mm)
      acc += al[h][mm] * __bfloat162float(pzl[mm][zc]);
    __syncthreads();
  }
  OPAIR[(size_t)n * 384 + t] = acc;
}

// ---------------- inverse rigid, norms, feature assembly, atom_vec ----------------
__global__ void finalize_k(
    const float* __restrict__ O, const float* __restrict__ OPTRAW,
    const float* __restrict__ OPAIR, const float* __restrict__ rot,
    const float* __restrict__ trans, const float* __restrict__ tfno_wv,
    float* __restrict__ RESF, float* __restrict__ ATOMF, float* __restrict__ ATOMVEC)
{
  const int n = blockIdx.x;
  const int t = threadIdx.x; // 256
  __shared__ float R[9], T[3];
  __shared__ float opt2[96][3];
  __shared__ float norml[96];
  if (t < 9) R[t] = rot[(size_t)n * 9 + t];
  if (t < 3) T[t] = trans[(size_t)n * 3 + t];
  __syncthreads();
  for (int idx = t; idx < 288; idx += 256) {
    int hp = idx / 3, i = idx % 3;
    float x = OPTRAW[(size_t)n * 288 + hp * 3 + 0] - T[0];
    float y = OPTRAW[(size_t)n * 288 + hp * 3 + 1] - T[1];
    float z = OPTRAW[(size_t)n * 288 + hp * 3 + 2] - T[2];
    opt2[hp][i] = R[0 + i] * x + R[3 + i] * y + R[6 + i] * z;  // rot^T
  }
  __syncthreads();
  if (t < 96)
    norml[t] = sqrtf(opt2[t][0] * opt2[t][0] + opt2[t][1] * opt2[t][1] +
                     opt2[t][2] * opt2[t][2] + 1e-8f);
  __syncthreads();
  const size_t rb = (size_t)n * 1536;
  const size_t ab = (size_t)n * 1248;
  for (int idx = t; idx < 768; idx += 256) {
    float v = O[(size_t)n * 768 + idx];
    RESF[rb + idx] = v;
    ATOMF[ab + idx] = v;
  }
  for (int idx = t; idx < 288; idx += 256) {
    int x = idx / 96, hp = idx % 96;
    RESF[rb + 768 + idx] = opt2[hp][x];
  }
  for (int idx = t; idx < 96; idx += 256) {
    RESF[rb + 1056 + idx] = norml[idx];
    ATOMF[ab + 768 + idx] = norml[idx];
  }
  for (int idx = t; idx < 384; idx += 256) {
    float v = OPAIR[(size_t)n * 384 + idx];
    RESF[rb + 1152 + idx] = v;
    ATOMF[ab + 864 + idx] = v;
  }
  for (int idx = t; idx < 192; idx += 256) {
    int o = idx / 3, x = idx % 3;
    float a = 0.f;
    for (int p = 0; p < 96; ++p) a += opt2[p][x] * tfno_wv[p * 64 + o];
    ATOMVEC[(size_t)n * 192 + idx] = a;
  }
}

// ---------------- final per-row selection ----------------
__global__ void select_k(const float* __restrict__ RESOUT, const float* __restrict__ ATOMSC,
                         const float* __restrict__ ATOMVEC, const int* __restrict__ ISA,
                         float* __restrict__ out) {
  int idx = blockIdx.x * 256 + threadIdx.x;
  if (idx < NN * 384) {
    int n = idx / 384, j = idx % 384;
    float v;
    if (ISA[n]) v = (j < 192) ? ATOMSC[(size_t)n * 192 + j] : ATOMVEC[(size_t)n * 192 + (j - 192)];
    else        v = RESOUT[idx];
    out[idx] = v;
  }
}

extern "C" void kernel_launch(void* const* d_in, const int* in_sizes, int n_in,
                              void* d_out, int out_size, void* d_ws, size_t ws_size,
                              hipStream_t stream) {
  (void)in_sizes; (void)n_in; (void)out_size; (void)ws_size;
  const float* s      = (const float*)d_in[0];
  const float* z      = (const float*)d_in[1];
  const float* rot    = (const float*)d_in[2];
  const float* trans  = (const float*)d_in[3];
  const float* mask   = (const float*)d_in[4];
  const float* wq     = (const float*)d_in[6];
  const float* bq     = (const float*)d_in[7];
  const float* wkv    = (const float*)d_in[8];
  const float* bkv    = (const float*)d_in[9];
  const float* wqp    = (const float*)d_in[10];
  const float* bqp    = (const float*)d_in[11];
  const float* wkvp   = (const float*)d_in[12];
  const float* bkvp   = (const float*)d_in[13];
  const float* wb     = (const float*)d_in[14];
  const float* bb     = (const float*)d_in[15];
  const float* wdz    = (const float*)d_in[16];
  const float* bdz    = (const float*)d_in[17];
  const float* head_w = (const float*)d_in[18];
  const float* wout   = (const float*)d_in[19];
  const float* bout   = (const float*)d_in[20];
  const float* tfnq_ws  = (const float*)d_in[21];
  const float* tfnq_wv  = (const float*)d_in[22];
  const float* tfnkv_ws = (const float*)d_in[23];
  const float* tfnkv_wv = (const float*)d_in[24];
  const float* tfno_ws  = (const float*)d_in[25];
  const float* tfno_wv  = (const float*)d_in[26];

  float* wsf = (float*)d_ws;
  int*   ISA   = (int*)(wsf + OFF_ISA);
  float* WCAT  = wsf + OFF_WCAT;
  float* QR    = wsf + OFF_QR;
  float* KVR   = wsf + OFF_KVR;
  float* QP    = wsf + OFF_QP;
  float* KVP   = wsf + OFF_KVP;
  float* QA    = wsf + OFF_QA;
  float* KVA   = wsf + OFF_KVA;
  float* QPA   = wsf + OFF_QPA;
  float* KVPA  = wsf + OFF_KVPA;
  float* Qb    = wsf + OFF_Q;
  float* Kb    = wsf + OFF_K;
  float* Vb    = wsf + OFF_V;
  float* QPTS  = wsf + OFF_QPTS;
  float* KPTS  = wsf + OFF_KPTS;
  float* VPTS  = wsf + OFF_VPTS;
  float* Abuf  = wsf + OFF_A;
  __hip_bfloat16* PZ = (__hip_bfloat16*)(wsf + OFF_PZ);
  float* Ob    = wsf + OFF_O;
  float* OPTRAW= wsf + OFF_OPTRAW;
  float* OPAIR = wsf + OFF_OPAIR;
  float* RESF  = wsf + OFF_RESF;
  float* ATOMF = wsf + OFF_ATOMF;
  float* RESOUT= wsf + OFF_RESOUT;
  float* ATOMSC= wsf + OFF_ATOMSC;
  float* ATOMVEC= wsf + OFF_ATOMVEC;

  detect_isa<<<1, 256, 0, stream>>>((const unsigned int*)d_in[5], ISA);
  build_wcat<<<22, 256, 0, stream>>>(wb, wdz, WCAT);

  // projections (residue + atom scalar parts)
  gemm_f32<<<dim3(12, 12), 256, 0, stream>>>(s, 384, wq, 768, bq, QR, 768, 768, 768, 384);
  gemm_f32<<<dim3(24, 12), 256, 0, stream>>>(s, 384, wkv, 1536, bkv, KVR, 1536, 768, 1536, 384);
  gemm_f32<<<dim3(3, 12), 256, 0, stream>>>(s, 384, wqp, 144, bqp, QP, 144, 768, 144, 384);
  gemm_f32<<<dim3(7, 12), 256, 0, stream>>>(s, 384, wkvp, 432, bkvp, KVP, 432, 768, 432, 384);
  gemm_f32<<<dim3(12, 12), 256, 0, stream>>>(s, 384, tfnq_ws, 768, nullptr, QA, 768, 768, 768, 192);
  gemm_f32<<<dim3(24, 12), 256, 0, stream>>>(s, 384, tfnkv_ws, 1536, nullptr, KVA, 1536, 768, 1536, 192);
  vec_proj<<<768, 192, 0, stream>>>(s, tfnq_wv, tfnkv_wv, trans, QPA, KVPA);
  rigid_select<<<768, 256, 0, stream>>>(QR, KVR, QP, KVP, QA, KVA, QPA, KVPA, rot, trans, ISA,
                                        Qb, Kb, Vb, QPTS, KPTS, VPTS);

  // z pass: bias term into Abuf h-planes, pair_z (bf16)
  zpass_gemm<<<9216, 256, 0, stream>>>(z, WCAT, bb, bdz, Abuf, PZ);

  // logits + softmax
  logits_k<<<dim3(12, 12, 12), 256, 0, stream>>>(Qb, Kb, QPTS, KPTS, mask, head_w, Abuf);
  softmax_k<<<9216, 256, 0, stream>>>(Abuf);

  // weighted sums
  attn_ov<<<dim3(24, 12), 256, 0, stream>>>(Abuf, Vb, VPTS, Ob, OPTRAW);
  attn_pair<<<768, 384, 0, stream>>>(Abuf, PZ, OPAIR);

  // finalize features + output GEMMs + select
  finalize_k<<<768, 256, 0, stream>>>(Ob, OPTRAW, OPAIR, rot, trans, tfno_wv, RESF, ATOMF, ATOMVEC);
  gemm_f32<<<dim3(6, 12), 256, 0, stream>>>(RESF, 1536, wout, 384, bout, RESOUT, 384, 768, 384, 1536);
  gemm_f32<<<dim3(3, 12), 256, 0, stream>>>(ATOMF, 1248, tfno_ws, 192, nullptr, ATOMSC, 192, 768, 192, 1248);
  select_k<<<1152, 256, 0, stream>>>(RESOUT, ATOMSC, ATOMVEC, ISA, (float*)d_out);
}

// Round 2
// 422.234 us; speedup vs baseline: 1.8603x; 1.8603x over previous
//
#include <hip/hip_runtime.h>
#include <hip/hip_bf16.h>

static constexpr int NN  = 768;
static constexpr int CSc = 384;

typedef short v8bf __attribute__((ext_vector_type(8)));   // 8 bf16 (4 VGPRs)
typedef float v4f  __attribute__((ext_vector_type(4)));

__device__ __forceinline__ unsigned short f2bf(float f) {
  unsigned u = __float_as_uint(f);
  u += 0x7fffu + ((u >> 16) & 1u);          // RNE
  return (unsigned short)(u >> 16);
}
__device__ __forceinline__ float bf2f(unsigned short s) {
  return __uint_as_float(((unsigned)s) << 16);
}

// -------- workspace layout (float units; all offsets multiple of 64) --------
static constexpr size_t OFF_ISA    = 0;                       // 1024 ints
static constexpr size_t OFF_WCT    = 1024;                    // 48x128 bf16
static constexpr size_t OFF_BCAT   = OFF_WCT + 3072;          // 48 f32 (pad 64)
static constexpr size_t OFF_SBF    = OFF_BCAT + 64;           // 768x384 bf16
static constexpr size_t OFF_WQT    = OFF_SBF + 147456;        // 768x384 bf16
static constexpr size_t OFF_WKVT   = OFF_WQT + 147456;        // 1536x384 bf16
static constexpr size_t OFF_WQPT   = OFF_WKVT + 294912;       // 192x384 bf16 (144 used)
static constexpr size_t OFF_WKVPT  = OFF_WQPT + 36864;        // 448x384 bf16 (432 used)
static constexpr size_t OFF_TFNQT  = OFF_WKVPT + 86016;       // 768x192 bf16
static constexpr size_t OFF_TFNKVT = OFF_TFNQT + 73728;       // 1536x192 bf16
static constexpr size_t OFF_WOUTT  = OFF_TFNKVT + 147456;     // 384x1536 bf16
static constexpr size_t OFF_TFNOT  = OFF_WOUTT + 294912;      // 192x1248 bf16
static constexpr size_t OFF_QR     = OFF_TFNOT + 119808;      // 768x768 f32
static constexpr size_t OFF_KVR    = OFF_QR + 589824;         // 768x1536 f32
static constexpr size_t OFF_QP     = OFF_KVR + 1179648;       // 768x144 f32
static constexpr size_t OFF_KVP    = OFF_QP + 110592;         // 768x432 f32
static constexpr size_t OFF_QA     = OFF_KVP + 331776;        // 768x768 f32
static constexpr size_t OFF_KVA    = OFF_QA + 589824;         // 768x1536 f32
static constexpr size_t OFF_QPA    = OFF_KVA + 1179648;       // 768x144 f32
static constexpr size_t OFF_KVPA   = OFF_QPA + 110592;        // 768x432 f32
static constexpr size_t OFF_QCAT   = OFF_KVPA + 331776;       // 768x12x96 bf16
static constexpr size_t OFF_KCAT   = OFF_QCAT + 442368;       // 768x12x96 bf16
static constexpr size_t OFF_RQ     = OFF_KCAT + 442368;       // 12x768 f32
static constexpr size_t OFF_RK     = OFF_RQ + 9216;           // 12x768 f32
static constexpr size_t OFF_VCATN  = OFF_RK + 9216;           // 768x12x96 f32
static constexpr size_t OFF_VCATT  = OFF_VCATN + 884736;      // 12x96x768 bf16
static constexpr size_t OFF_BB     = OFF_VCATT + 442368;      // 12x768x768 bf16
static constexpr size_t OFF_PZT    = OFF_BB + 3538944;        // 768x32x768 bf16
static constexpr size_t OFF_ABUF   = OFF_PZT + 9437184;       // 12x768x768 f32
static constexpr size_t OFF_ABF    = OFF_ABUF + 7077888;      // 12x768x768 bf16
static constexpr size_t OFF_OPTRAW = OFF_ABF + 3538944;       // 768x288 f32
static constexpr size_t OFF_RESF   = OFF_OPTRAW + 221184;     // 768x1536 bf16
static constexpr size_t OFF_ATOMF  = OFF_RESF + 589824;       // 768x1248 bf16
static constexpr size_t OFF_AVEC   = OFF_ATOMF + 479232;      // 768x192 f32
static constexpr size_t OFF_RESOUT = OFF_AVEC + 147456;       // 768x384 f32
static constexpr size_t OFF_ATOMSC = OFF_RESOUT + 294912;     // 768x192 f32

// ---------------- is_atom dtype detection ----------------
__global__ void detect_isa(const unsigned int* __restrict__ u, int* __restrict__ ISA) {
  __shared__ int notint, notfloat;
  const int t = threadIdx.x;
  if (t == 0) { notint = 0; notfloat = 0; }
  __syncthreads();
  if (t < 192) {
    unsigned v = u[t];
    if (v > 1u) atomicOr(&notint, 1);
    if (v != 0u && v != 0x3F800000u) atomicOr(&notfloat, 1);
  }
  __syncthreads();
  const int mode = (!notint) ? 0 : ((!notfloat) ? 1 : 2);
  for (int n = t; n < NN; n += 256) {
    int val;
    if (mode == 2) val = (((const unsigned char*)u)[n] != 0);
    else           val = (u[n] != 0u);
    ISA[n] = val;
  }
}

// ---------------- WCT (48x128 bf16, transposed, scaled) + bcat ----------------
__global__ void build_wcatb(const float* __restrict__ wb, const float* __restrict__ wdz,
                            const float* __restrict__ bb, const float* __restrict__ bdz,
                            unsigned short* __restrict__ WCT, float* __restrict__ bcat) {
  const float rs3 = 0.57735026918962576f;
  int idx = blockIdx.x * 256 + threadIdx.x;
  if (idx < 48 * 128) {
    int o = idx >> 7, k = idx & 127;
    float v = 0.f;
    if (o < 12) v = rs3 * wb[k * 12 + o];
    else if (o < 44) v = wdz[k * 32 + (o - 12)];
    WCT[o * 128 + k] = f2bf(v);
  }
  if (blockIdx.x == 0 && threadIdx.x < 48) {
    int o = threadIdx.x;
    bcat[o] = (o < 12) ? rs3 * bb[o] : (o < 44 ? bdz[o - 12] : 0.f);
  }
}

// ---------------- weight transpose-convert (f32 [K][N] -> bf16 [N][K]) ----------------
struct CvArgs {
  const float* src[9];
  unsigned short* dst[9];
  int K[9], N[9], mode[9];   // mode 0 = transpose, 1 = direct convert
};

__global__ __launch_bounds__(256) void convert_wt(CvArgs a) {
  const int z = blockIdx.z;
  const int K = a.K[z], N = a.N[z];
  const float* src = a.src[z];
  unsigned short* dst = a.dst[z];
  if (a.mode[z] == 1) {
    long long total = (long long)K * N;
    long long base = ((long long)blockIdx.y * gridDim.x + blockIdx.x) * 1024 + threadIdx.x * 4;
    if (base + 3 < total) {
      float4 v = *(const float4*)(src + base);
      unsigned short tmp[4] = {f2bf(v.x), f2bf(v.y), f2bf(v.z), f2bf(v.w)};
      *(uint2*)(dst + base) = *(uint2*)tmp;
    } else {
      for (int j = 0; j < 4; ++j) if (base + j < total) dst[base + j] = f2bf(src[base + j]);
    }
    return;
  }
  __shared__ float tl[32][33];
  const int k0 = blockIdx.y * 32, n0 = blockIdx.x * 32;
  if (k0 >= K || n0 >= N) return;
  const int tx = threadIdx.x & 31, ty = threadIdx.x >> 5;
  for (int it = 0; it < 4; ++it) {
    int r = ty + it * 8;
    float v = 0.f;
    if (k0 + r < K && n0 + tx < N) v = src[(long long)(k0 + r) * N + n0 + tx];
    tl[r][tx] = v;
  }
  __syncthreads();
  for (int it = 0; it < 4; ++it) {
    int r = ty + it * 8;   // local n
    if (n0 + r < N && k0 + tx < K)
      dst[(long long)(n0 + r) * K + k0 + tx] = f2bf(tl[tx][r]);
  }
}

// ---------------- generic MFMA GEMM: C(f32) = A_bf[M][lda] @ BT_bf[N][ldb]^T + bias ----
__global__ __launch_bounds__(256) void gemm_mfma(
    const unsigned short* __restrict__ A, int lda,
    const unsigned short* __restrict__ BT, int ldb,
    const float* __restrict__ bias,
    float* __restrict__ C, int ldc, int M, int Nc, int K)
{
  const int w = threadIdx.x >> 6, l = threadIdx.x & 63;
  const int l15 = l & 15, lg = l >> 4;
  const int rowA = blockIdx.y * 64 + w * 16 + l15;
  const int colb = blockIdx.x * 64;
  v4f acc[4] = {};
  const unsigned short* ap = A + (long long)rowA * lda + lg * 8;
  for (int k0 = 0; k0 < K; k0 += 32) {
    v8bf av = *(const v8bf*)(ap + k0);
#pragma unroll
    for (int cf = 0; cf < 4; ++cf) {
      v8bf bv = *(const v8bf*)(BT + (long long)(colb + cf * 16 + l15) * ldb + k0 + lg * 8);
      acc[cf] = __builtin_amdgcn_mfma_f32_16x16x32_bf16(av, bv, acc[cf], 0, 0, 0);
    }
  }
  const int r0 = blockIdx.y * 64 + w * 16 + lg * 4;
#pragma unroll
  for (int cf = 0; cf < 4; ++cf) {
    int c = colb + cf * 16 + l15;
    if (c < Nc) {
      float bv = bias ? bias[c] : 0.f;
#pragma unroll
      for (int i = 0; i < 4; ++i) {
        int r = r0 + i;
        if (r < M) C[(long long)r * ldc + c] = acc[cf][i] + bv;
      }
    }
  }
}

// ---------------- atom-path point projections from vec (f32, tiny) ----------------
__global__ void vec_proj(
    const float* __restrict__ s, const float* __restrict__ tfnq_wv,
    const float* __restrict__ tfnkv_wv, const float* __restrict__ trans,
    float* __restrict__ QPA, float* __restrict__ KVPA)
{
  const int n = blockIdx.x;
  const int t = threadIdx.x; // 192
  __shared__ float sv[192];
  sv[t] = s[(size_t)n * CSc + 192 + t];
  __syncthreads();
  if (t < 144) {
    int o = t / 3, x = t % 3;
    float a = 0.f;
    for (int i = 0; i < 64; ++i) a += sv[i * 3 + x] * tfnq_wv[i * 48 + o];
    QPA[(size_t)n * 144 + t] = a + trans[n * 3 + x];
  }
  for (int idx = t; idx < 432; idx += 192) {
    int o = idx / 3, x = idx % 3;
    float a = 0.f;
    for (int i = 0; i < 64; ++i) a += sv[i * 3 + x] * tfnkv_wv[i * 144 + o];
    KVPA[(size_t)n * 432 + idx] = a + trans[n * 3 + x];
  }
}

// ---------------- rigid transform + selection -> Qcat/Kcat/Vcatn/rq/rk ----------------
__global__ __launch_bounds__(256) void rigid_select(
    const float* __restrict__ QR, const float* __restrict__ KVR,
    const float* __restrict__ QP, const float* __restrict__ KVP,
    const float* __restrict__ QA, const float* __restrict__ KVA,
    const float* __restrict__ QPA, const float* __restrict__ KVPA,
    const float* __restrict__ rot, const float* __restrict__ trans,
    const float* __restrict__ head_w, const int* __restrict__ ISA,
    unsigned short* __restrict__ Qcat, unsigned short* __restrict__ Kcat,
    float* __restrict__ rq, float* __restrict__ rk, float* __restrict__ Vcatn)
{
  const int n = blockIdx.x, t = threadIdx.x;
  const bool isa = ISA[n] != 0;
  __shared__ float R[9], T[3], shw[12];
  __shared__ float qs[768], ks[768], vs[768], qp[144], kp[144], vp[288];
  if (t < 9) R[t] = rot[n * 9 + t];
  if (t < 3) T[t] = trans[n * 3 + t];
  if (t >= 16 && t < 28) {
    int h = t - 16;
    shw[h] = log1pf(__expf(head_w[h])) * 0.13608276348795434f;  // softplus*sqrt(1/54)
  }
  __syncthreads();
  for (int idx = t; idx < 768; idx += 256) {
    int h = idx >> 6, c = idx & 63;
    qs[idx] = isa ? QA[(long long)n * 768 + idx] : QR[(long long)n * 768 + idx];
    ks[idx] = isa ? KVA[(long long)n * 1536 + h * 128 + c] : KVR[(long long)n * 1536 + h * 128 + c];
    vs[idx] = isa ? KVA[(long long)n * 1536 + h * 128 + 64 + c] : KVR[(long long)n * 1536 + h * 128 + 64 + c];
  }
  for (int idx = t; idx < 144; idx += 256) {
    int hp = idx / 3, i = idx % 3;
    float v;
    if (isa) v = QPA[(long long)n * 144 + idx];
    else
      v = R[i * 3 + 0] * QP[(long long)n * 144 + 0 + hp] +
          R[i * 3 + 1] * QP[(long long)n * 144 + 48 + hp] +
          R[i * 3 + 2] * QP[(long long)n * 144 + 96 + hp] + T[i];
    qp[idx] = v;
  }
  for (int idx = t; idx < 432; idx += 256) {
    int hp = idx / 3, i = idx % 3;
    float v;
    if (isa) v = KVPA[(long long)n * 432 + idx];
    else
      v = R[i * 3 + 0] * KVP[(long long)n * 432 + 0 + hp] +
          R[i * 3 + 1] * KVP[(long long)n * 432 + 144 + hp] +
          R[i * 3 + 2] * KVP[(long long)n * 432 + 288 + hp] + T[i];
    int h = hp / 12, pp = hp % 12;
    if (pp < 4) kp[(h * 4 + pp) * 3 + i] = v;
    else        vp[(h * 8 + (pp - 4)) * 3 + i] = v;
  }
  __syncthreads();
  const float sq = 0.07216878364870322f;  // sqrt(1/192)
  for (int idx = t; idx < 1152; idx += 256) {
    int h = idx / 96, c = idx % 96;
    float qv = (c < 64) ? sq * qs[h * 64 + c] : ((c < 76) ? shw[h] * qp[h * 12 + (c - 64)] : 0.f);
    float kv = (c < 64) ? ks[h * 64 + c]      : ((c < 76) ? kp[h * 12 + (c - 64)] : 0.f);
    float vv = (c < 64) ? vs[h * 64 + c]      : ((c < 88) ? vp[h * 24 + (c - 64)] : 0.f);
    long long base = ((long long)n * 12 + h) * 96 + c;
    Qcat[base] = f2bf(qv);
    Kcat[base] = f2bf(kv);
    Vcatn[base] = vv;
  }
  if (t < 24) {
    int h = t >> 1, which = t & 1;
    const float* p = which ? kp : qp;
    float s2 = 0.f;
#pragma unroll
    for (int d = 0; d < 12; ++d) { float x = p[h * 12 + d]; s2 += x * x; }
    float val = 0.5f * shw[h] * s2;
    if (which) rk[h * 768 + n] = val;
    else       rq[h * 768 + n] = val;
  }
}

// ---------------- Vcat transpose: [n][h][96] f32 -> [h][96][768] bf16 ----------------
__global__ __launch_bounds__(256) void vcat_t(const float* __restrict__ Vcatn,
                                              unsigned short* __restrict__ VcatT) {
  const int h = blockIdx.y, n0 = blockIdx.x * 64, t = threadIdx.x;
  __shared__ float tl[64][97];
  for (int idx = t; idx < 64 * 96; idx += 256) {
    int r = idx / 96, c = idx % 96;
    tl[r][c] = Vcatn[((long long)(n0 + r) * 12 + h) * 96 + c];
  }
  __syncthreads();
  for (int idx = t; idx < 96 * 4; idx += 256) {
    int c = idx >> 2, seg = idx & 3;
    unsigned short tmp[16];
#pragma unroll
    for (int j = 0; j < 16; ++j) tmp[j] = f2bf(tl[seg * 16 + j][c]);
    unsigned short* gp = VcatT + ((long long)h * 96 + c) * 768 + n0 + seg * 16;
    *(uint4*)gp = *(uint4*)tmp;
    *(uint4*)(gp + 8) = *(uint4*)(tmp + 8);
  }
}

// ---------------- z pass (MFMA): Bb bf16 + PZT bf16 (transposed) ----------------
__global__ __launch_bounds__(256) void zpass_mfma(
    const float* __restrict__ Z, const unsigned short* __restrict__ WCT,
    const float* __restrict__ bcat,
    unsigned short* __restrict__ Bb, unsigned short* __restrict__ PZT)
{
  __shared__ __align__(16) char smraw[128 * 136 * 2];   // 34816 B
  unsigned short* Abf = (unsigned short*)smraw;
  float* Sout = (float*)smraw;                           // reused after barrier (25344 B)
  const int t = threadIdx.x;
  const long long row0 = (long long)blockIdx.x * 128;
  // stage z tile -> bf16 LDS (padded stride 136)
  for (int i = 0; i < 16; ++i) {
    int fi = (i * 256 + t) * 4;
    float4 v = *(const float4*)(Z + row0 * 128 + fi);
    int r = fi >> 7, c = fi & 127;
    unsigned short tmp[4] = {f2bf(v.x), f2bf(v.y), f2bf(v.z), f2bf(v.w)};
    *(uint2*)(Abf + r * 136 + c) = *(uint2*)tmp;
  }
  __syncthreads();
  const int w = t >> 6, l = t & 63, l15 = l & 15, lg = l >> 4;
  v4f acc[2][3] = {};
  for (int ks = 0; ks < 4; ++ks) {
    v8bf bvv[3];
#pragma unroll
    for (int cf = 0; cf < 3; ++cf)
      bvv[cf] = *(const v8bf*)(WCT + (cf * 16 + l15) * 128 + ks * 32 + lg * 8);
#pragma unroll
    for (int rf = 0; rf < 2; ++rf) {
      v8bf av = *(const v8bf*)(Abf + (w * 32 + rf * 16 + l15) * 136 + ks * 32 + lg * 8);
#pragma unroll
      for (int cf = 0; cf < 3; ++cf)
        acc[rf][cf] = __builtin_amdgcn_mfma_f32_16x16x32_bf16(av, bvv[cf], acc[rf][cf], 0, 0, 0);
    }
  }
  __syncthreads();
  // stage D -> Sout[o][m] (f32) for coalesced m-major global writes
#pragma unroll
  for (int rf = 0; rf < 2; ++rf)
#pragma unroll
    for (int cf = 0; cf < 3; ++cf) {
      int o = cf * 16 + l15;
#pragma unroll
      for (int i = 0; i < 4; ++i) {
        int m = w * 32 + rf * 16 + lg * 4 + i;
        Sout[o * 132 + m] = acc[rf][cf][i];
      }
    }
  __syncthreads();
  const int n = blockIdx.x / 6;
  const int m0 = (blockIdx.x % 6) * 128;
  for (int idx = t; idx < 44 * 8; idx += 256) {
    int o = idx >> 3, seg = idx & 7;
    float bias = bcat[o];
    unsigned short tmp[16];
#pragma unroll
    for (int j = 0; j < 16; ++j) tmp[j] = f2bf(Sout[o * 132 + seg * 16 + j] + bias);
    unsigned short* gp;
    if (o < 12) gp = Bb + ((long long)o * 768 + n) * 768 + m0 + seg * 16;
    else        gp = PZT + ((long long)n * 32 + (o - 12)) * 768 + m0 + seg * 16;
    *(uint4*)gp = *(uint4*)tmp;
    *(uint4*)(gp + 8) = *(uint4*)(tmp + 8);
  }
}

// ---------------- logits (MFMA over K=96: qk + point cross term) ----------------
__global__ __launch_bounds__(256) void logits_mfma(
    const unsigned short* __restrict__ Qcat, const unsigned short* __restrict__ Kcat,
    const unsigned short* __restrict__ Bb, const float* __restrict__ rq,
    const float* __restrict__ rk, const float* __restrict__ mask,
    float* __restrict__ Abuf)
{
  const int h = blockIdx.z, nt = blockIdx.y, mt = blockIdx.x;
  const int t = threadIdx.x, w = t >> 6, l = t & 63, l15 = l & 15, lg = l >> 4;
  const int nrow = nt * 64 + w * 16 + l15;
  v8bf aq[3];
#pragma unroll
  for (int ks = 0; ks < 3; ++ks)
    aq[ks] = *(const v8bf*)(Qcat + ((long long)nrow * 12 + h) * 96 + ks * 32 + lg * 8);
  v4f acc[12] = {};
#pragma unroll
  for (int cf = 0; cf < 12; ++cf) {
    int m = mt * 192 + cf * 16 + l15;
    const unsigned short* kb = Kcat + ((long long)m * 12 + h) * 96 + lg * 8;
#pragma unroll
    for (int ks = 0; ks < 3; ++ks) {
      v8bf bv = *(const v8bf*)(kb + ks * 32);
      acc[cf] = __builtin_amdgcn_mfma_f32_16x16x32_bf16(aq[ks], bv, acc[cf], 0, 0, 0);
    }
  }
  const int r0 = nt * 64 + w * 16 + lg * 4;
#pragma unroll
  for (int cf = 0; cf < 12; ++cf) {
    int m = mt * 192 + cf * 16 + l15;
    float rkm = rk[h * 768 + m], maskm = mask[m];
#pragma unroll
    for (int i = 0; i < 4; ++i) {
      int nn = r0 + i;
      float v = acc[cf][i]
              + bf2f(Bb[((long long)h * 768 + nn) * 768 + m])
              - rq[h * 768 + nn] - rkm
              + 100000.0f * (mask[nn] * maskm - 1.0f);
      Abuf[((long long)h * 768 + nn) * 768 + m] = v;
    }
  }
}

// ---------------- row softmax f32 -> bf16 ----------------
__global__ __launch_bounds__(256) void softmax_bf(const float* __restrict__ Abuf,
                                                  unsigned short* __restrict__ Abf) {
  const long long r = (long long)blockIdx.x * 768;
  const int t = threadIdx.x;
  float v0 = Abuf[r + t], v1 = Abuf[r + t + 256], v2 = Abuf[r + t + 512];
  float mx = fmaxf(v0, fmaxf(v1, v2));
#pragma unroll
  for (int off = 32; off > 0; off >>= 1) mx = fmaxf(mx, __shfl_xor(mx, off, 64));
  __shared__ float red[4], red2[4];
  const int wid = t >> 6, lane = t & 63;
  if (lane == 0) red[wid] = mx;
  __syncthreads();
  mx = fmaxf(fmaxf(red[0], red[1]), fmaxf(red[2], red[3]));
  float e0 = __expf(v0 - mx), e1 = __expf(v1 - mx), e2 = __expf(v2 - mx);
  float sm = e0 + e1 + e2;
#pragma unroll
  for (int off = 32; off > 0; off >>= 1) sm += __shfl_xor(sm, off, 64);
  if (lane == 0) red2[wid] = sm;
  __syncthreads();
  sm = red2[0] + red2[1] + red2[2] + red2[3];
  float inv = 1.0f / sm;
  Abf[r + t] = f2bf(e0 * inv);
  Abf[r + t + 256] = f2bf(e1 * inv);
  Abf[r + t + 512] = f2bf(e2 * inv);
}

// ---------------- o / o_pt accumulation (MFMA) ----------------
__global__ __launch_bounds__(256) void attn_ov_mfma(
    const unsigned short* __restrict__ Abf, const unsigned short* __restrict__ VcatT,
    unsigned short* __restrict__ RESF, unsigned short* __restrict__ ATOMF,
    float* __restrict__ OPTRAW)
{
  const int h = blockIdx.y, nt = blockIdx.x;
  const int t = threadIdx.x, w = t >> 6, l = t & 63, l15 = l & 15, lg = l >> 4;
  const int nrow = nt * 64 + w * 16 + l15;
  const unsigned short* arow = Abf + ((long long)h * 768 + nrow) * 768 + lg * 8;
  const unsigned short* vbase = VcatT + (long long)h * 96 * 768 + lg * 8;
  v4f acc[6] = {};
  for (int k0 = 0; k0 < 768; k0 += 32) {
    v8bf av = *(const v8bf*)(arow + k0);
#pragma unroll
    for (int cf = 0; cf < 6; ++cf) {
      v8bf bv = *(const v8bf*)(vbase + (long long)(cf * 16 + l15) * 768 + k0);
      acc[cf] = __builtin_amdgcn_mfma_f32_16x16x32_bf16(av, bv, acc[cf], 0, 0, 0);
    }
  }
  const int r0 = nt * 64 + w * 16 + lg * 4;
#pragma unroll
  for (int cf = 0; cf < 6; ++cf) {
    int c = cf * 16 + l15;
#pragma unroll
    for (int i = 0; i < 4; ++i) {
      int n = r0 + i;
      float v = acc[cf][i];
      if (c < 64) {
        unsigned short b = f2bf(v);
        RESF[(long long)n * 1536 + h * 64 + c] = b;
        ATOMF[(long long)n * 1248 + h * 64 + c] = b;
      } else if (c < 88) {
        OPTRAW[(long long)n * 288 + h * 24 + (c - 64)] = v;
      }
    }
  }
}

// ---------------- o_pair accumulation (MFMA) ----------------
__global__ __launch_bounds__(256) void attn_pair_mfma(
    const unsigned short* __restrict__ Abf, const unsigned short* __restrict__ PZT,
    unsigned short* __restrict__ RESF, unsigned short* __restrict__ ATOMF)
{
  const int t = threadIdx.x, w = t >> 6, l = t & 63, l15 = l & 15, lg = l >> 4;
  const int n = blockIdx.x * 4 + w;
  const int hh = (l15 < 12) ? l15 : 0;   // rows 12..15 are discarded
  const unsigned short* arow = Abf + ((long long)hh * 768 + n) * 768 + lg * 8;
  const unsigned short* pz = PZT + (long long)n * 32 * 768 + lg * 8;
  v4f acc[2] = {};
  for (int k0 = 0; k0 < 768; k0 += 32) {
    v8bf av = *(const v8bf*)(arow + k0);
#pragma unroll
    for (int cf = 0; cf < 2; ++cf) {
      v8bf bv = *(const v8bf*)(pz + (long long)(cf * 16 + l15) * 768 + k0);
      acc[cf] = __builtin_amdgcn_mfma_f32_16x16x32_bf16(av, bv, acc[cf], 0, 0, 0);
    }
  }
#pragma unroll
  for (int cf = 0; cf < 2; ++cf) {
    int zc = cf * 16 + l15;
#pragma unroll
    for (int i = 0; i < 4; ++i) {
      int hd = lg * 4 + i;
      if (hd < 12) {
        unsigned short b = f2bf(acc[cf][i]);
        RESF[(long long)n * 1536 + 1152 + hd * 32 + zc] = b;
        ATOMF[(long long)n * 1248 + 864 + hd * 32 + zc] = b;
      }
    }
  }
}

// ---------------- inverse rigid, norms, feats, atom_vec ----------------
__global__ void finalize_k(
    const float* __restrict__ OPTRAW, const float* __restrict__ rot,
    const float* __restrict__ trans, const float* __restrict__ tfno_wv,
    unsigned short* __restrict__ RESF, unsigned short* __restrict__ ATOMF,
    float* __restrict__ ATOMVEC)
{
  const int n = blockIdx.x, t = threadIdx.x;
  __shared__ float R[9], T[3], opt2[96][3], norml[96];
  if (t < 9) R[t] = rot[(size_t)n * 9 + t];
  if (t < 3) T[t] = trans[(size_t)n * 3 + t];
  __syncthreads();
  for (int idx = t; idx < 288; idx += 256) {
    int hp = idx / 3, i = idx % 3;
    float x = OPTRAW[(size_t)n * 288 + hp * 3 + 0] - T[0];
    float y = OPTRAW[(size_t)n * 288 + hp * 3 + 1] - T[1];
    float z = OPTRAW[(size_t)n * 288 + hp * 3 + 2] - T[2];
    opt2[hp][i] = R[0 + i] * x + R[3 + i] * y + R[6 + i] * z;  // rot^T
  }
  __syncthreads();
  if (t < 96)
    norml[t] = sqrtf(opt2[t][0] * opt2[t][0] + opt2[t][1] * opt2[t][1] +
                     opt2[t][2] * opt2[t][2] + 1e-8f);
  __syncthreads();
  const long long rb = (long long)n * 1536;
  const long long ab = (long long)n * 1248;
  for (int idx = t; idx < 288; idx += 256) {
    int x = idx / 96, hp = idx % 96;
    RESF[rb + 768 + idx] = f2bf(opt2[hp][x]);
  }
  for (int idx = t; idx < 96; idx += 256) {
    unsigned short b = f2bf(norml[idx]);
    RESF[rb + 1056 + idx] = b;
    ATOMF[ab + 768 + idx] = b;
  }
  for (int idx = t; idx < 192; idx += 256) {
    int o = idx / 3, x = idx % 3;
    float a = 0.f;
    for (int p = 0; p < 96; ++p) a += opt2[p][x] * tfno_wv[p * 64 + o];
    ATOMVEC[(size_t)n * 192 + idx] = a;
  }
}

// ---------------- final per-row selection ----------------
__global__ void select_k(const float* __restrict__ RESOUT, const float* __restrict__ ATOMSC,
                         const float* __restrict__ ATOMVEC, const int* __restrict__ ISA,
                         float* __restrict__ out) {
  int idx = blockIdx.x * 256 + threadIdx.x;
  if (idx < NN * 384) {
    int n = idx / 384, j = idx % 384;
    float v;
    if (ISA[n]) v = (j < 192) ? ATOMSC[(size_t)n * 192 + j] : ATOMVEC[(size_t)n * 192 + (j - 192)];
    else        v = RESOUT[idx];
    out[idx] = v;
  }
}

extern "C" void kernel_launch(void* const* d_in, const int* in_sizes, int n_in,
                              void* d_out, int out_size, void* d_ws, size_t ws_size,
                              hipStream_t stream) {
  (void)in_sizes; (void)n_in; (void)out_size; (void)ws_size;
  const float* s      = (const float*)d_in[0];
  const float* z      = (const float*)d_in[1];
  const float* rot    = (const float*)d_in[2];
  const float* trans  = (const float*)d_in[3];
  const float* mask   = (const float*)d_in[4];
  const float* wq     = (const float*)d_in[6];
  const float* bq     = (const float*)d_in[7];
  const float* wkv    = (const float*)d_in[8];
  const float* bkv    = (const float*)d_in[9];
  const float* wqp    = (const float*)d_in[10];
  const float* bqp    = (const float*)d_in[11];
  const float* wkvp   = (const float*)d_in[12];
  const float* bkvp   = (const float*)d_in[13];
  const float* wb     = (const float*)d_in[14];
  const float* bb     = (const float*)d_in[15];
  const float* wdz    = (const float*)d_in[16];
  const float* bdz    = (const float*)d_in[17];
  const float* head_w = (const float*)d_in[18];
  const float* wout   = (const float*)d_in[19];
  const float* bout   = (const float*)d_in[20];
  const float* tfnq_ws  = (const float*)d_in[21];
  const float* tfnq_wv  = (const float*)d_in[22];
  const float* tfnkv_ws = (const float*)d_in[23];
  const float* tfnkv_wv = (const float*)d_in[24];
  const float* tfno_ws  = (const float*)d_in[25];
  const float* tfno_wv  = (const float*)d_in[26];

  float* wsf = (float*)d_ws;
  int* ISA = (int*)(wsf + OFF_ISA);
  unsigned short* WCT    = (unsigned short*)(wsf + OFF_WCT);
  float*          BCAT   = wsf + OFF_BCAT;
  unsigned short* SBF    = (unsigned short*)(wsf + OFF_SBF);
  unsigned short* WQT    = (unsigned short*)(wsf + OFF_WQT);
  unsigned short* WKVT   = (unsigned short*)(wsf + OFF_WKVT);
  unsigned short* WQPT   = (unsigned short*)(wsf + OFF_WQPT);
  unsigned short* WKVPT  = (unsigned short*)(wsf + OFF_WKVPT);
  unsigned short* TFNQT  = (unsigned short*)(wsf + OFF_TFNQT);
  unsigned short* TFNKVT = (unsigned short*)(wsf + OFF_TFNKVT);
  unsigned short* WOUTT  = (unsigned short*)(wsf + OFF_WOUTT);
  unsigned short* TFNOT  = (unsigned short*)(wsf + OFF_TFNOT);
  float* QR   = wsf + OFF_QR;
  float* KVR  = wsf + OFF_KVR;
  float* QP   = wsf + OFF_QP;
  float* KVP  = wsf + OFF_KVP;
  float* QA   = wsf + OFF_QA;
  float* KVA  = wsf + OFF_KVA;
  float* QPA  = wsf + OFF_QPA;
  float* KVPA = wsf + OFF_KVPA;
  unsigned short* QCAT  = (unsigned short*)(wsf + OFF_QCAT);
  unsigned short* KCAT  = (unsigned short*)(wsf + OFF_KCAT);
  float* RQ    = wsf + OFF_RQ;
  float* RK    = wsf + OFF_RK;
  float* VCATN = wsf + OFF_VCATN;
  unsigned short* VCATT = (unsigned short*)(wsf + OFF_VCATT);
  unsigned short* BBUF  = (unsigned short*)(wsf + OFF_BB);
  unsigned short* PZT   = (unsigned short*)(wsf + OFF_PZT);
  float* ABUF  = wsf + OFF_ABUF;
  unsigned short* ABF   = (unsigned short*)(wsf + OFF_ABF);
  float* OPTRAW = wsf + OFF_OPTRAW;
  unsigned short* RESF  = (unsigned short*)(wsf + OFF_RESF);
  unsigned short* ATOMF = (unsigned short*)(wsf + OFF_ATOMF);
  float* AVEC   = wsf + OFF_AVEC;
  float* RESOUT = wsf + OFF_RESOUT;
  float* ATOMSC = wsf + OFF_ATOMSC;

  detect_isa<<<1, 256, 0, stream>>>((const unsigned int*)d_in[5], ISA);
  build_wcatb<<<24, 256, 0, stream>>>(wb, wdz, bb, bdz, WCT, BCAT);

  CvArgs cv;
  cv.src[0] = wq;       cv.dst[0] = WQT;    cv.K[0] = 384;  cv.N[0] = 768;  cv.mode[0] = 0;
  cv.src[1] = wkv;      cv.dst[1] = WKVT;   cv.K[1] = 384;  cv.N[1] = 1536; cv.mode[1] = 0;
  cv.src[2] = wqp;      cv.dst[2] = WQPT;   cv.K[2] = 384;  cv.N[2] = 144;  cv.mode[2] = 0;
  cv.src[3] = wkvp;     cv.dst[3] = WKVPT;  cv.K[3] = 384;  cv.N[3] = 432;  cv.mode[3] = 0;
  cv.src[4] = tfnq_ws;  cv.dst[4] = TFNQT;  cv.K[4] = 192;  cv.N[4] = 768;  cv.mode[4] = 0;
  cv.src[5] = tfnkv_ws; cv.dst[5] = TFNKVT; cv.K[5] = 192;  cv.N[5] = 1536; cv.mode[5] = 0;
  cv.src[6] = wout;     cv.dst[6] = WOUTT;  cv.K[6] = 1536; cv.N[6] = 384;  cv.mode[6] = 0;
  cv.src[7] = tfno_ws;  cv.dst[7] = TFNOT;  cv.K[7] = 1248; cv.N[7] = 192;  cv.mode[7] = 0;
  cv.src[8] = s;        cv.dst[8] = SBF;    cv.K[8] = 768;  cv.N[8] = 384;  cv.mode[8] = 1;
  convert_wt<<<dim3(48, 48, 9), 256, 0, stream>>>(cv);

  // projections (MFMA)
  gemm_mfma<<<dim3(12, 12), 256, 0, stream>>>(SBF, 384, WQT,    384, bq,      QR,  768,  768, 768,  384);
  gemm_mfma<<<dim3(24, 12), 256, 0, stream>>>(SBF, 384, WKVT,   384, bkv,     KVR, 1536, 768, 1536, 384);
  gemm_mfma<<<dim3(3, 12),  256, 0, stream>>>(SBF, 384, WQPT,   384, bqp,     QP,  144,  768, 144,  384);
  gemm_mfma<<<dim3(7, 12),  256, 0, stream>>>(SBF, 384, WKVPT,  384, bkvp,    KVP, 432,  768, 432,  384);
  gemm_mfma<<<dim3(12, 12), 256, 0, stream>>>(SBF, 384, TFNQT,  192, nullptr, QA,  768,  768, 768,  192);
  gemm_mfma<<<dim3(24, 12), 256, 0, stream>>>(SBF, 384, TFNKVT, 192, nullptr, KVA, 1536, 768, 1536, 192);

  vec_proj<<<768, 192, 0, stream>>>(s, tfnq_wv, tfnkv_wv, trans, QPA, KVPA);
  rigid_select<<<768, 256, 0, stream>>>(QR, KVR, QP, KVP, QA, KVA, QPA, KVPA,
                                        rot, trans, head_w, ISA,
                                        QCAT, KCAT, RQ, RK, VCATN);
  vcat_t<<<dim3(12, 12), 256, 0, stream>>>(VCATN, VCATT);

  // z pass
  zpass_mfma<<<4608, 256, 0, stream>>>(z, WCT, BCAT, BBUF, PZT);

  // logits + softmax
  logits_mfma<<<dim3(4, 12, 12), 256, 0, stream>>>(QCAT, KCAT, BBUF, RQ, RK, mask, ABUF);
  softmax_bf<<<9216, 256, 0, stream>>>(ABUF, ABF);

  // weighted sums
  attn_ov_mfma<<<dim3(12, 12), 256, 0, stream>>>(ABF, VCATT, RESF, ATOMF, OPTRAW);
  attn_pair_mfma<<<192, 256, 0, stream>>>(ABF, PZT, RESF, ATOMF);

  // finalize + output GEMMs + select
  finalize_k<<<768, 256, 0, stream>>>(OPTRAW, rot, trans, tfno_wv, RESF, ATOMF, AVEC);
  gemm_mfma<<<dim3(6, 12), 256, 0, stream>>>(RESF, 1536, WOUTT, 1536, bout,    RESOUT, 384, 768, 384, 1536);
  gemm_mfma<<<dim3(3, 12), 256, 0, stream>>>(ATOMF, 1248, TFNOT, 1248, nullptr, ATOMSC, 192, 768, 192, 1248);
  select_k<<<1152, 256, 0, stream>>>(RESOUT, ATOMSC, AVEC, ISA, (float*)d_out);
}

// Round 3
// 279.454 us; speedup vs baseline: 2.8107x; 1.5109x over previous
//
#include <hip/hip_runtime.h>
#include <hip/hip_bf16.h>

static constexpr int NN  = 768;

typedef short v8bf __attribute__((ext_vector_type(8)));   // 8 bf16 (4 VGPRs)
typedef float v4f  __attribute__((ext_vector_type(4)));

__device__ __forceinline__ unsigned short f2bf(float f) {
  unsigned u = __float_as_uint(f);
  u += 0x7fffu + ((u >> 16) & 1u);          // RNE
  return (unsigned short)(u >> 16);
}
__device__ __forceinline__ float bf2f(unsigned short s) {
  return __uint_as_float(((unsigned)s) << 16);
}

// -------- workspace layout (float units) --------
static constexpr size_t OFF_ISA    = 0;                       // 1024 ints
static constexpr size_t OFF_WCT    = 1024;                    // 48x128 bf16
static constexpr size_t OFF_BCAT   = OFF_WCT + 3072;          // 48 f32 (pad 64)
static constexpr size_t OFF_SBF    = OFF_BCAT + 64;           // 768x384 bf16
static constexpr size_t OFF_WQT    = OFF_SBF + 147456;        // 768x384 bf16
static constexpr size_t OFF_WKVT   = OFF_WQT + 147456;        // 1536x384 bf16
static constexpr size_t OFF_WQPT   = OFF_WKVT + 294912;       // 192x384 bf16 (144 used)
static constexpr size_t OFF_WKVPT  = OFF_WQPT + 36864;        // 448x384 bf16 (432 used)
static constexpr size_t OFF_TFNQT  = OFF_WKVPT + 86016;       // 768x192 bf16
static constexpr size_t OFF_TFNKVT = OFF_TFNQT + 73728;       // 1536x192 bf16
static constexpr size_t OFF_WOUTT  = OFF_TFNKVT + 147456;     // 384x1536 bf16
static constexpr size_t OFF_TFNOT  = OFF_WOUTT + 294912;      // 192x1248 bf16
static constexpr size_t OFF_QR     = OFF_TFNOT + 119808;      // 768x768 f32
static constexpr size_t OFF_KVR    = OFF_QR + 589824;         // 768x1536 f32
static constexpr size_t OFF_QP     = OFF_KVR + 1179648;       // 768x144 f32
static constexpr size_t OFF_KVP    = OFF_QP + 110592;         // 768x432 f32
static constexpr size_t OFF_QA     = OFF_KVP + 331776;        // 768x768 f32
static constexpr size_t OFF_KVA    = OFF_QA + 589824;         // 768x1536 f32
static constexpr size_t OFF_QCAT   = OFF_KVA + 1179648;       // 768x12x96 bf16
static constexpr size_t OFF_KCAT   = OFF_QCAT + 442368;       // 768x12x96 bf16
static constexpr size_t OFF_RQ     = OFF_KCAT + 442368;       // 12x768 f32
static constexpr size_t OFF_RK     = OFF_RQ + 9216;           // 12x768 f32
static constexpr size_t OFF_VCATN  = OFF_RK + 9216;           // 768x12x96 f32
static constexpr size_t OFF_VCATT  = OFF_VCATN + 884736;      // 12x96x768 bf16
static constexpr size_t OFF_BB     = OFF_VCATT + 442368;      // 12x768x768 bf16
static constexpr size_t OFF_PZT    = OFF_BB + 3538944;        // 768x32x768 bf16
static constexpr size_t OFF_ABF    = OFF_PZT + 9437184;       // 12x768x768 bf16
static constexpr size_t OFF_OPTRAW = OFF_ABF + 3538944;       // 768x288 f32
static constexpr size_t OFF_RESF   = OFF_OPTRAW + 221184;     // 768x1536 bf16
static constexpr size_t OFF_ATOMF  = OFF_RESF + 589824;       // 768x1248 bf16
static constexpr size_t OFF_AVEC   = OFF_ATOMF + 479232;      // 768x192 f32
static constexpr size_t OFF_RESOUT = OFF_AVEC + 147456;       // 768x384 f32
static constexpr size_t OFF_ATOMSC = OFF_RESOUT + 294912;     // 768x192 f32

// ---------------- is_atom dtype detection ----------------
__global__ void detect_isa(const unsigned int* __restrict__ u, int* __restrict__ ISA) {
  __shared__ int notint, notfloat;
  const int t = threadIdx.x;
  if (t == 0) { notint = 0; notfloat = 0; }
  __syncthreads();
  if (t < 192) {
    unsigned v = u[t];
    if (v > 1u) atomicOr(&notint, 1);
    if (v != 0u && v != 0x3F800000u) atomicOr(&notfloat, 1);
  }
  __syncthreads();
  const int mode = (!notint) ? 0 : ((!notfloat) ? 1 : 2);
  for (int n = t; n < NN; n += 256) {
    int val;
    if (mode == 2) val = (((const unsigned char*)u)[n] != 0);
    else           val = (u[n] != 0u);
    ISA[n] = val;
  }
}

// ---------------- WCT (48x128 bf16, transposed, scaled) + bcat ----------------
__global__ void build_wcatb(const float* __restrict__ wb, const float* __restrict__ wdz,
                            const float* __restrict__ bb, const float* __restrict__ bdz,
                            unsigned short* __restrict__ WCT, float* __restrict__ bcat) {
  const float rs3 = 0.57735026918962576f;
  int idx = blockIdx.x * 256 + threadIdx.x;
  if (idx < 48 * 128) {
    int o = idx >> 7, k = idx & 127;
    float v = 0.f;
    if (o < 12) v = rs3 * wb[k * 12 + o];
    else if (o < 44) v = wdz[k * 32 + (o - 12)];
    WCT[o * 128 + k] = f2bf(v);
  }
  if (blockIdx.x == 0 && threadIdx.x < 48) {
    int o = threadIdx.x;
    bcat[o] = (o < 12) ? rs3 * bb[o] : (o < 44 ? bdz[o - 12] : 0.f);
  }
}

// ---------------- weight transpose-convert (f32 [K][N] -> bf16 [N][K]) ----------------
struct CvArgs {
  const float* src[9];
  unsigned short* dst[9];
  int K[9], N[9], mode[9];   // mode 0 = transpose, 1 = direct convert
};

__global__ __launch_bounds__(256) void convert_wt(CvArgs a) {
  const int z = blockIdx.z;
  const int K = a.K[z], N = a.N[z];
  const float* src = a.src[z];
  unsigned short* dst = a.dst[z];
  if (a.mode[z] == 1) {
    long long total = (long long)K * N;
    long long base = ((long long)blockIdx.y * gridDim.x + blockIdx.x) * 1024 + threadIdx.x * 4;
    if (base + 3 < total) {
      float4 v = *(const float4*)(src + base);
      unsigned short tmp[4] = {f2bf(v.x), f2bf(v.y), f2bf(v.z), f2bf(v.w)};
      *(uint2*)(dst + base) = *(uint2*)tmp;
    } else {
      for (int j = 0; j < 4; ++j) if (base + j < total) dst[base + j] = f2bf(src[base + j]);
    }
    return;
  }
  __shared__ float tl[32][33];
  const int k0 = blockIdx.y * 32, n0 = blockIdx.x * 32;
  if (k0 >= K || n0 >= N) return;
  const int tx = threadIdx.x & 31, ty = threadIdx.x >> 5;
  for (int it = 0; it < 4; ++it) {
    int r = ty + it * 8;
    float v = 0.f;
    if (k0 + r < K && n0 + tx < N) v = src[(long long)(k0 + r) * N + n0 + tx];
    tl[r][tx] = v;
  }
  __syncthreads();
  for (int it = 0; it < 4; ++it) {
    int r = ty + it * 8;   // local n
    if (n0 + r < N && k0 + tx < K)
      dst[(long long)(n0 + r) * K + k0 + tx] = f2bf(tl[tx][r]);
  }
}

// ---------------- multi-segment MFMA GEMM (M=768 rows) ----------------
struct GM {
  const unsigned short* A[6];
  const unsigned short* BT[6];
  const float* bias[6];
  float* C[6];
  int lda[6], ldb[6], ldc[6], Nc[6], K[6];
  int xoff[8];
  int nseg;
};

__global__ __launch_bounds__(256) void gemm_multi(GM g) {
  int bx = blockIdx.x, si = 0;
  while (si + 1 < g.nseg && bx >= g.xoff[si + 1]) ++si;
  const int xt = bx - g.xoff[si];
  const unsigned short* A = g.A[si];
  const unsigned short* BT = g.BT[si];
  const float* bias = g.bias[si];
  float* C = g.C[si];
  const int lda = g.lda[si], ldb = g.ldb[si], ldc = g.ldc[si];
  const int Nc = g.Nc[si], K = g.K[si];
  const int w = threadIdx.x >> 6, l = threadIdx.x & 63;
  const int l15 = l & 15, lg = l >> 4;
  const int rowA = blockIdx.y * 64 + w * 16 + l15;
  const int colb = xt * 64;
  v4f acc[4] = {};
  const unsigned short* ap = A + (long long)rowA * lda + lg * 8;
  for (int k0 = 0; k0 < K; k0 += 32) {
    v8bf av = *(const v8bf*)(ap + k0);
#pragma unroll
    for (int cf = 0; cf < 4; ++cf) {
      v8bf bv = *(const v8bf*)(BT + (long long)(colb + cf * 16 + l15) * ldb + k0 + lg * 8);
      acc[cf] = __builtin_amdgcn_mfma_f32_16x16x32_bf16(av, bv, acc[cf], 0, 0, 0);
    }
  }
  const int r0 = blockIdx.y * 64 + w * 16 + lg * 4;
#pragma unroll
  for (int cf = 0; cf < 4; ++cf) {
    int c = colb + cf * 16 + l15;
    if (c < Nc) {
      float bv = bias ? bias[c] : 0.f;
#pragma unroll
      for (int i = 0; i < 4; ++i)
        C[(long long)(r0 + i) * ldc + c] = acc[cf][i] + bv;
    }
  }
}

// ---------------- prep: vec_proj + rigid transform + selection ----------------
__global__ __launch_bounds__(256) void prep_qkv(
    const float* __restrict__ s,
    const float* __restrict__ QR, const float* __restrict__ KVR,
    const float* __restrict__ QP, const float* __restrict__ KVP,
    const float* __restrict__ QA, const float* __restrict__ KVA,
    const float* __restrict__ rot, const float* __restrict__ trans,
    const float* __restrict__ head_w,
    const float* __restrict__ tfnq_wv, const float* __restrict__ tfnkv_wv,
    const int* __restrict__ ISA,
    unsigned short* __restrict__ Qcat, unsigned short* __restrict__ Kcat,
    float* __restrict__ rq, float* __restrict__ rk, float* __restrict__ Vcatn)
{
  const int n = blockIdx.x, t = threadIdx.x;
  const bool isa = ISA[n] != 0;
  __shared__ float R[9], T[3], shw[12], sv[192];
  __shared__ float qs[768], ks[768], vs[768], qp[144], kp[144], vp[288];
  if (t < 9) R[t] = rot[n * 9 + t];
  if (t < 3) T[t] = trans[n * 3 + t];
  if (t >= 16 && t < 28)
    shw[t - 16] = log1pf(__expf(head_w[t - 16])) * 0.13608276348795434f; // softplus*sqrt(1/54)
  if (isa && t >= 32 && t < 224) sv[t - 32] = s[(size_t)n * 384 + 192 + (t - 32)];
  __syncthreads();
  for (int idx = t; idx < 768; idx += 256) {
    int h = idx >> 6, c = idx & 63;
    qs[idx] = isa ? QA[(long long)n * 768 + idx] : QR[(long long)n * 768 + idx];
    ks[idx] = isa ? KVA[(long long)n * 1536 + h * 128 + c] : KVR[(long long)n * 1536 + h * 128 + c];
    vs[idx] = isa ? KVA[(long long)n * 1536 + h * 128 + 64 + c] : KVR[(long long)n * 1536 + h * 128 + 64 + c];
  }
  if (isa) {
    for (int idx = t; idx < 144; idx += 256) {
      int hp = idx / 3, x = idx % 3;
      float a = 0.f;
      for (int i = 0; i < 64; ++i) a += sv[i * 3 + x] * tfnq_wv[i * 48 + hp];
      qp[idx] = a + T[x];
    }
    for (int idx = t; idx < 432; idx += 256) {
      int o = idx / 3, x = idx % 3;
      float a = 0.f;
      for (int i = 0; i < 64; ++i) a += sv[i * 3 + x] * tfnkv_wv[i * 144 + o];
      float v = a + T[x];
      int h = o / 12, pp = o % 12;
      if (pp < 4) kp[(h * 4 + pp) * 3 + x] = v;
      else        vp[(h * 8 + (pp - 4)) * 3 + x] = v;
    }
  } else {
    for (int idx = t; idx < 144; idx += 256) {
      int hp = idx / 3, i = idx % 3;
      qp[idx] = R[i * 3 + 0] * QP[(long long)n * 144 + 0 + hp] +
                R[i * 3 + 1] * QP[(long long)n * 144 + 48 + hp] +
                R[i * 3 + 2] * QP[(long long)n * 144 + 96 + hp] + T[i];
    }
    for (int idx = t; idx < 432; idx += 256) {
      int hp = idx / 3, i = idx % 3;
      float v = R[i * 3 + 0] * KVP[(long long)n * 432 + 0 + hp] +
                R[i * 3 + 1] * KVP[(long long)n * 432 + 144 + hp] +
                R[i * 3 + 2] * KVP[(long long)n * 432 + 288 + hp] + T[i];
      int h = hp / 12, pp = hp % 12;
      if (pp < 4) kp[(h * 4 + pp) * 3 + i] = v;
      else        vp[(h * 8 + (pp - 4)) * 3 + i] = v;
    }
  }
  __syncthreads();
  const float sq = 0.07216878364870322f;  // sqrt(1/192)
  for (int idx = t; idx < 1152; idx += 256) {
    int h = idx / 96, c = idx % 96;
    float qv = (c < 64) ? sq * qs[h * 64 + c] : ((c < 76) ? shw[h] * qp[h * 12 + (c - 64)] : 0.f);
    float kv = (c < 64) ? ks[h * 64 + c]      : ((c < 76) ? kp[h * 12 + (c - 64)] : 0.f);
    float vv = (c < 64) ? vs[h * 64 + c]      : ((c < 88) ? vp[h * 24 + (c - 64)] : 0.f);
    long long base = ((long long)n * 12 + h) * 96 + c;
    Qcat[base] = f2bf(qv);
    Kcat[base] = f2bf(kv);
    Vcatn[base] = vv;
  }
  if (t < 24) {
    int h = t >> 1, which = t & 1;
    const float* p = which ? kp : qp;
    float s2 = 0.f;
#pragma unroll
    for (int d = 0; d < 12; ++d) { float x = p[h * 12 + d]; s2 += x * x; }
    float val = 0.5f * shw[h] * s2;
    if (which) rk[h * 768 + n] = val;
    else       rq[h * 768 + n] = val;
  }
}

// ---------------- Vcat transpose: [n][h][96] f32 -> [h][96][768] bf16 ----------------
__global__ __launch_bounds__(256) void vcat_t(const float* __restrict__ Vcatn,
                                              unsigned short* __restrict__ VcatT) {
  const int h = blockIdx.y, n0 = blockIdx.x * 64, t = threadIdx.x;
  __shared__ float tl[64][97];
  for (int idx = t; idx < 64 * 96; idx += 256) {
    int r = idx / 96, c = idx % 96;
    tl[r][c] = Vcatn[((long long)(n0 + r) * 12 + h) * 96 + c];
  }
  __syncthreads();
  for (int idx = t; idx < 96 * 4; idx += 256) {
    int c = idx >> 2, seg = idx & 3;
    unsigned short tmp[16];
#pragma unroll
    for (int j = 0; j < 16; ++j) tmp[j] = f2bf(tl[seg * 16 + j][c]);
    unsigned short* gp = VcatT + ((long long)h * 96 + c) * 768 + n0 + seg * 16;
    *(uint4*)gp = *(uint4*)tmp;
    *(uint4*)(gp + 8) = *(uint4*)(tmp + 8);
  }
}

// ---------------- z pass (MFMA): Bb bf16 + PZT bf16 (transposed) ----------------
__global__ __launch_bounds__(256) void zpass_mfma(
    const float* __restrict__ Z, const unsigned short* __restrict__ WCT,
    const float* __restrict__ bcat,
    unsigned short* __restrict__ Bb, unsigned short* __restrict__ PZT)
{
  __shared__ __align__(16) char smraw[128 * 136 * 2];   // 34816 B
  unsigned short* Abf = (unsigned short*)smraw;
  float* Sout = (float*)smraw;                           // reused after barrier
  const int t = threadIdx.x;
  const long long row0 = (long long)blockIdx.x * 128;
  for (int i = 0; i < 16; ++i) {
    int fi = (i * 256 + t) * 4;
    float4 v = *(const float4*)(Z + row0 * 128 + fi);
    int r = fi >> 7, c = fi & 127;
    unsigned short tmp[4] = {f2bf(v.x), f2bf(v.y), f2bf(v.z), f2bf(v.w)};
    *(uint2*)(Abf + r * 136 + c) = *(uint2*)tmp;
  }
  __syncthreads();
  const int w = t >> 6, l = t & 63, l15 = l & 15, lg = l >> 4;
  v4f acc[2][3] = {};
  for (int ks = 0; ks < 4; ++ks) {
    v8bf bvv[3];
#pragma unroll
    for (int cf = 0; cf < 3; ++cf)
      bvv[cf] = *(const v8bf*)(WCT + (cf * 16 + l15) * 128 + ks * 32 + lg * 8);
#pragma unroll
    for (int rf = 0; rf < 2; ++rf) {
      v8bf av = *(const v8bf*)(Abf + (w * 32 + rf * 16 + l15) * 136 + ks * 32 + lg * 8);
#pragma unroll
      for (int cf = 0; cf < 3; ++cf)
        acc[rf][cf] = __builtin_amdgcn_mfma_f32_16x16x32_bf16(av, bvv[cf], acc[rf][cf], 0, 0, 0);
    }
  }
  __syncthreads();
#pragma unroll
  for (int rf = 0; rf < 2; ++rf)
#pragma unroll
    for (int cf = 0; cf < 3; ++cf) {
      int o = cf * 16 + l15;
#pragma unroll
      for (int i = 0; i < 4; ++i) {
        int m = w * 32 + rf * 16 + lg * 4 + i;
        Sout[o * 132 + m] = acc[rf][cf][i];
      }
    }
  __syncthreads();
  const int n = blockIdx.x / 6;
  const int m0 = (blockIdx.x % 6) * 128;
  for (int idx = t; idx < 44 * 8; idx += 256) {
    int o = idx >> 3, seg = idx & 7;
    float bias = bcat[o];
    unsigned short tmp[16];
#pragma unroll
    for (int j = 0; j < 16; ++j) tmp[j] = f2bf(Sout[o * 132 + seg * 16 + j] + bias);
    unsigned short* gp;
    if (o < 12) gp = Bb + ((long long)o * 768 + n) * 768 + m0 + seg * 16;
    else        gp = PZT + ((long long)n * 32 + (o - 12)) * 768 + m0 + seg * 16;
    *(uint4*)gp = *(uint4*)tmp;
    *(uint4*)(gp + 8) = *(uint4*)(tmp + 8);
  }
}

// ---------------- fused logits + softmax -> bf16 A ----------------
__global__ __launch_bounds__(256) void logits_soft(
    const unsigned short* __restrict__ Qcat, const unsigned short* __restrict__ Kcat,
    const unsigned short* __restrict__ Bb, const float* __restrict__ rq,
    const float* __restrict__ rk, const float* __restrict__ mask,
    unsigned short* __restrict__ Abf)
{
  constexpr int LSTR = 778;
  __shared__ float S[16 * LSTR];      // 16 rows x 768 f32 (stride 778)
  __shared__ float invs[16];
  const int h = blockIdx.y;
  const int r0 = blockIdx.x * 16;
  const int t = threadIdx.x, w = t >> 6, l = t & 63, l15 = l & 15, lg = l >> 4;
  // wave w computes m in [w*192, w*192+192) for rows r0..r0+15
  const int nrow = r0 + l15;
  v8bf aq[3];
#pragma unroll
  for (int ks = 0; ks < 3; ++ks)
    aq[ks] = *(const v8bf*)(Qcat + ((long long)nrow * 12 + h) * 96 + ks * 32 + lg * 8);
  v4f acc[12] = {};
#pragma unroll
  for (int cf = 0; cf < 12; ++cf) {
    int m = w * 192 + cf * 16 + l15;
    const unsigned short* kb = Kcat + ((long long)m * 12 + h) * 96 + lg * 8;
#pragma unroll
    for (int ks = 0; ks < 3; ++ks) {
      v8bf bv = *(const v8bf*)(kb + ks * 32);
      acc[cf] = __builtin_amdgcn_mfma_f32_16x16x32_bf16(aq[ks], bv, acc[cf], 0, 0, 0);
    }
  }
  float rqn[4], mskn[4];
#pragma unroll
  for (int i = 0; i < 4; ++i) {
    int gn = r0 + lg * 4 + i;
    rqn[i] = rq[h * 768 + gn];
    mskn[i] = mask[gn];
  }
#pragma unroll
  for (int cf = 0; cf < 12; ++cf) {
    int m = w * 192 + cf * 16 + l15;
    float rkm = rk[h * 768 + m], maskm = mask[m];
#pragma unroll
    for (int i = 0; i < 4; ++i) {
      int rl = lg * 4 + i;
      float v = acc[cf][i] + bf2f(Bb[((long long)h * 768 + r0 + rl) * 768 + m])
              - rqn[i] - rkm + 100000.0f * (mskn[i] * maskm - 1.0f);
      S[rl * LSTR + m] = v;
    }
  }
  __syncthreads();
  {
    const int row = t >> 4, sub = t & 15;
    float mx = -3.0e38f;
    for (int c = sub; c < 768; c += 16) mx = fmaxf(mx, S[row * LSTR + c]);
#pragma unroll
    for (int off = 1; off < 16; off <<= 1) mx = fmaxf(mx, __shfl_xor(mx, off, 64));
    float sm = 0.f;
    for (int c = sub; c < 768; c += 16) {
      float e = __expf(S[row * LSTR + c] - mx);
      S[row * LSTR + c] = e;
      sm += e;
    }
#pragma unroll
    for (int off = 1; off < 16; off <<= 1) sm += __shfl_xor(sm, off, 64);
    if (sub == 0) invs[row] = 1.0f / sm;
  }
  __syncthreads();
  for (int row = 0; row < 16; ++row) {
    float inv = invs[row];
    unsigned short* dst = Abf + ((long long)h * 768 + r0 + row) * 768;
#pragma unroll
    for (int cb = 0; cb < 3; ++cb) {
      int col = cb * 256 + t;
      dst[col] = f2bf(S[row * LSTR + col] * inv);
    }
  }
}

// ---------------- o / o_pt accumulation (MFMA, split-K over waves) ----------------
__global__ __launch_bounds__(256) void attn_ov_mfma(
    const unsigned short* __restrict__ Abf, const unsigned short* __restrict__ VcatT,
    unsigned short* __restrict__ RESF, unsigned short* __restrict__ ATOMF,
    float* __restrict__ OPTRAW)
{
  __shared__ v4f PS[24][64];
  const int h = blockIdx.y, nt = blockIdx.x;   // 48 x-blocks, 16 rows each
  const int t = threadIdx.x, w = t >> 6, l = t & 63, l15 = l & 15, lg = l >> 4;
  const int nrow = nt * 16 + l15;
  const unsigned short* arow = Abf + ((long long)h * 768 + nrow) * 768 + lg * 8;
  const unsigned short* vbase = VcatT + (long long)h * 96 * 768 + lg * 8;
  v4f acc[6] = {};
  for (int k0 = w * 192; k0 < w * 192 + 192; k0 += 32) {
    v8bf av = *(const v8bf*)(arow + k0);
#pragma unroll
    for (int cf = 0; cf < 6; ++cf) {
      v8bf bv = *(const v8bf*)(vbase + (long long)(cf * 16 + l15) * 768 + k0);
      acc[cf] = __builtin_amdgcn_mfma_f32_16x16x32_bf16(av, bv, acc[cf], 0, 0, 0);
    }
  }
#pragma unroll
  for (int cf = 0; cf < 6; ++cf) PS[w * 6 + cf][l] = acc[cf];
  __syncthreads();
  const int grp = t >> 6;
  for (int cf = grp; cf < 6; cf += 4) {
    v4f sv = PS[cf][l] + PS[6 + cf][l] + PS[12 + cf][l] + PS[18 + cf][l];
    int c = cf * 16 + l15;
    int rb = nt * 16 + lg * 4;
#pragma unroll
    for (int i = 0; i < 4; ++i) {
      int n = rb + i;
      float v = sv[i];
      if (c < 64) {
        unsigned short b = f2bf(v);
        RESF[(long long)n * 1536 + h * 64 + c] = b;
        ATOMF[(long long)n * 1248 + h * 64 + c] = b;
      } else if (c < 88) {
        OPTRAW[(long long)n * 288 + h * 24 + (c - 64)] = v;
      }
    }
  }
}

// ---------------- o_pair accumulation (MFMA, split-K over waves) ----------------
__global__ __launch_bounds__(256) void attn_pair_mfma(
    const unsigned short* __restrict__ Abf, const unsigned short* __restrict__ PZT,
    unsigned short* __restrict__ RESF, unsigned short* __restrict__ ATOMF)
{
  __shared__ v4f PS[8][64];
  const int n = blockIdx.x;
  const int t = threadIdx.x, w = t >> 6, l = t & 63, l15 = l & 15, lg = l >> 4;
  const int hh = (l15 < 12) ? l15 : 0;
  const unsigned short* arow = Abf + ((long long)hh * 768 + n) * 768 + lg * 8;
  const unsigned short* pz = PZT + (long long)n * 32 * 768 + lg * 8;
  v4f acc[2] = {};
  for (int k0 = w * 192; k0 < w * 192 + 192; k0 += 32) {
    v8bf av = *(const v8bf*)(arow + k0);
#pragma unroll
    for (int cf = 0; cf < 2; ++cf) {
      v8bf bv = *(const v8bf*)(pz + (long long)(cf * 16 + l15) * 768 + k0);
      acc[cf] = __builtin_amdgcn_mfma_f32_16x16x32_bf16(av, bv, acc[cf], 0, 0, 0);
    }
  }
  PS[w * 2 + 0][l] = acc[0];
  PS[w * 2 + 1][l] = acc[1];
  __syncthreads();
  if (t < 128) {
    int cf = t >> 6, ll = t & 63;
    v4f sv = PS[cf][ll] + PS[2 + cf][ll] + PS[4 + cf][ll] + PS[6 + cf][ll];
    int zc = cf * 16 + (ll & 15);
#pragma unroll
    for (int i = 0; i < 4; ++i) {
      int hd = (ll >> 4) * 4 + i;
      if (hd < 12) {
        unsigned short b = f2bf(sv[i]);
        RESF[(long long)n * 1536 + 1152 + hd * 32 + zc] = b;
        ATOMF[(long long)n * 1248 + 864 + hd * 32 + zc] = b;
      }
    }
  }
}

// ---------------- inverse rigid, norms, feats, atom_vec ----------------
__global__ void finalize_k(
    const float* __restrict__ OPTRAW, const float* __restrict__ rot,
    const float* __restrict__ trans, const float* __restrict__ tfno_wv,
    unsigned short* __restrict__ RESF, unsigned short* __restrict__ ATOMF,
    float* __restrict__ ATOMVEC)
{
  const int n = blockIdx.x, t = threadIdx.x;
  __shared__ float R[9], T[3], opt2[96][3], norml[96];
  if (t < 9) R[t] = rot[(size_t)n * 9 + t];
  if (t < 3) T[t] = trans[(size_t)n * 3 + t];
  __syncthreads();
  for (int idx = t; idx < 288; idx += 256) {
    int hp = idx / 3, i = idx % 3;
    float x = OPTRAW[(size_t)n * 288 + hp * 3 + 0] - T[0];
    float y = OPTRAW[(size_t)n * 288 + hp * 3 + 1] - T[1];
    float z = OPTRAW[(size_t)n * 288 + hp * 3 + 2] - T[2];
    opt2[hp][i] = R[0 + i] * x + R[3 + i] * y + R[6 + i] * z;  // rot^T
  }
  __syncthreads();
  if (t < 96)
    norml[t] = sqrtf(opt2[t][0] * opt2[t][0] + opt2[t][1] * opt2[t][1] +
                     opt2[t][2] * opt2[t][2] + 1e-8f);
  __syncthreads();
  const long long rb = (long long)n * 1536;
  const long long ab = (long long)n * 1248;
  for (int idx = t; idx < 288; idx += 256) {
    int x = idx / 96, hp = idx % 96;
    RESF[rb + 768 + idx] = f2bf(opt2[hp][x]);
  }
  for (int idx = t; idx < 96; idx += 256) {
    unsigned short b = f2bf(norml[idx]);
    RESF[rb + 1056 + idx] = b;
    ATOMF[ab + 768 + idx] = b;
  }
  for (int idx = t; idx < 192; idx += 256) {
    int o = idx / 3, x = idx % 3;
    float a = 0.f;
    for (int p = 0; p < 96; ++p) a += opt2[p][x] * tfno_wv[p * 64 + o];
    ATOMVEC[(size_t)n * 192 + idx] = a;
  }
}

// ---------------- final per-row selection ----------------
__global__ void select_k(const float* __restrict__ RESOUT, const float* __restrict__ ATOMSC,
                         const float* __restrict__ ATOMVEC, const int* __restrict__ ISA,
                         float* __restrict__ out) {
  int idx = blockIdx.x * 256 + threadIdx.x;
  if (idx < NN * 384) {
    int n = idx / 384, j = idx % 384;
    float v;
    if (ISA[n]) v = (j < 192) ? ATOMSC[(size_t)n * 192 + j] : ATOMVEC[(size_t)n * 192 + (j - 192)];
    else        v = RESOUT[idx];
    out[idx] = v;
  }
}

extern "C" void kernel_launch(void* const* d_in, const int* in_sizes, int n_in,
                              void* d_out, int out_size, void* d_ws, size_t ws_size,
                              hipStream_t stream) {
  (void)in_sizes; (void)n_in; (void)out_size; (void)ws_size;
  const float* s      = (const float*)d_in[0];
  const float* z      = (const float*)d_in[1];
  const float* rot    = (const float*)d_in[2];
  const float* trans  = (const float*)d_in[3];
  const float* mask   = (const float*)d_in[4];
  const float* wq     = (const float*)d_in[6];
  const float* bq     = (const float*)d_in[7];
  const float* wkv    = (const float*)d_in[8];
  const float* bkv    = (const float*)d_in[9];
  const float* wqp    = (const float*)d_in[10];
  const float* bqp    = (const float*)d_in[11];
  const float* wkvp   = (const float*)d_in[12];
  const float* bkvp   = (const float*)d_in[13];
  const float* wb     = (const float*)d_in[14];
  const float* bb     = (const float*)d_in[15];
  const float* wdz    = (const float*)d_in[16];
  const float* bdz    = (const float*)d_in[17];
  const float* head_w = (const float*)d_in[18];
  const float* wout   = (const float*)d_in[19];
  const float* bout   = (const float*)d_in[20];
  const float* tfnq_ws  = (const float*)d_in[21];
  const float* tfnq_wv  = (const float*)d_in[22];
  const float* tfnkv_ws = (const float*)d_in[23];
  const float* tfnkv_wv = (const float*)d_in[24];
  const float* tfno_ws  = (const float*)d_in[25];
  const float* tfno_wv  = (const float*)d_in[26];

  float* wsf = (float*)d_ws;
  int* ISA = (int*)(wsf + OFF_ISA);
  unsigned short* WCT    = (unsigned short*)(wsf + OFF_WCT);
  float*          BCAT   = wsf + OFF_BCAT;
  unsigned short* SBF    = (unsigned short*)(wsf + OFF_SBF);
  unsigned short* WQT    = (unsigned short*)(wsf + OFF_WQT);
  unsigned short* WKVT   = (unsigned short*)(wsf + OFF_WKVT);
  unsigned short* WQPT   = (unsigned short*)(wsf + OFF_WQPT);
  unsigned short* WKVPT  = (unsigned short*)(wsf + OFF_WKVPT);
  unsigned short* TFNQT  = (unsigned short*)(wsf + OFF_TFNQT);
  unsigned short* TFNKVT = (unsigned short*)(wsf + OFF_TFNKVT);
  unsigned short* WOUTT  = (unsigned short*)(wsf + OFF_WOUTT);
  unsigned short* TFNOT  = (unsigned short*)(wsf + OFF_TFNOT);
  float* QR   = wsf + OFF_QR;
  float* KVR  = wsf + OFF_KVR;
  float* QP   = wsf + OFF_QP;
  float* KVP  = wsf + OFF_KVP;
  float* QA   = wsf + OFF_QA;
  float* KVA  = wsf + OFF_KVA;
  unsigned short* QCAT  = (unsigned short*)(wsf + OFF_QCAT);
  unsigned short* KCAT  = (unsigned short*)(wsf + OFF_KCAT);
  float* RQ    = wsf + OFF_RQ;
  float* RK    = wsf + OFF_RK;
  float* VCATN = wsf + OFF_VCATN;
  unsigned short* VCATT = (unsigned short*)(wsf + OFF_VCATT);
  unsigned short* BBUF  = (unsigned short*)(wsf + OFF_BB);
  unsigned short* PZT   = (unsigned short*)(wsf + OFF_PZT);
  unsigned short* ABF   = (unsigned short*)(wsf + OFF_ABF);
  float* OPTRAW = wsf + OFF_OPTRAW;
  unsigned short* RESF  = (unsigned short*)(wsf + OFF_RESF);
  unsigned short* ATOMF = (unsigned short*)(wsf + OFF_ATOMF);
  float* AVEC   = wsf + OFF_AVEC;
  float* RESOUT = wsf + OFF_RESOUT;
  float* ATOMSC = wsf + OFF_ATOMSC;

  detect_isa<<<1, 256, 0, stream>>>((const unsigned int*)d_in[5], ISA);
  build_wcatb<<<24, 256, 0, stream>>>(wb, wdz, bb, bdz, WCT, BCAT);

  CvArgs cv;
  cv.src[0] = wq;       cv.dst[0] = WQT;    cv.K[0] = 384;  cv.N[0] = 768;  cv.mode[0] = 0;
  cv.src[1] = wkv;      cv.dst[1] = WKVT;   cv.K[1] = 384;  cv.N[1] = 1536; cv.mode[1] = 0;
  cv.src[2] = wqp;      cv.dst[2] = WQPT;   cv.K[2] = 384;  cv.N[2] = 144;  cv.mode[2] = 0;
  cv.src[3] = wkvp;     cv.dst[3] = WKVPT;  cv.K[3] = 384;  cv.N[3] = 432;  cv.mode[3] = 0;
  cv.src[4] = tfnq_ws;  cv.dst[4] = TFNQT;  cv.K[4] = 192;  cv.N[4] = 768;  cv.mode[4] = 0;
  cv.src[5] = tfnkv_ws; cv.dst[5] = TFNKVT; cv.K[5] = 192;  cv.N[5] = 1536; cv.mode[5] = 0;
  cv.src[6] = wout;     cv.dst[6] = WOUTT;  cv.K[6] = 1536; cv.N[6] = 384;  cv.mode[6] = 0;
  cv.src[7] = tfno_ws;  cv.dst[7] = TFNOT;  cv.K[7] = 1248; cv.N[7] = 192;  cv.mode[7] = 0;
  cv.src[8] = s;        cv.dst[8] = SBF;    cv.K[8] = 768;  cv.N[8] = 384;  cv.mode[8] = 1;
  convert_wt<<<dim3(48, 48, 9), 256, 0, stream>>>(cv);

  // z pass (independent of projections; longest kernel)
  zpass_mfma<<<4608, 256, 0, stream>>>(z, WCT, BCAT, BBUF, PZT);

  // projections: one merged launch (6 segments)
  GM gp_;
  gp_.A[0]=SBF; gp_.BT[0]=WQT;    gp_.bias[0]=bq;      gp_.C[0]=QR;  gp_.lda[0]=384; gp_.ldb[0]=384; gp_.ldc[0]=768;  gp_.Nc[0]=768;  gp_.K[0]=384;
  gp_.A[1]=SBF; gp_.BT[1]=WKVT;   gp_.bias[1]=bkv;     gp_.C[1]=KVR; gp_.lda[1]=384; gp_.ldb[1]=384; gp_.ldc[1]=1536; gp_.Nc[1]=1536; gp_.K[1]=384;
  gp_.A[2]=SBF; gp_.BT[2]=WQPT;   gp_.bias[2]=bqp;     gp_.C[2]=QP;  gp_.lda[2]=384; gp_.ldb[2]=384; gp_.ldc[2]=144;  gp_.Nc[2]=144;  gp_.K[2]=384;
  gp_.A[3]=SBF; gp_.BT[3]=WKVPT;  gp_.bias[3]=bkvp;    gp_.C[3]=KVP; gp_.lda[3]=384; gp_.ldb[3]=384; gp_.ldc[3]=432;  gp_.Nc[3]=432;  gp_.K[3]=384;
  gp_.A[4]=SBF; gp_.BT[4]=TFNQT;  gp_.bias[4]=nullptr; gp_.C[4]=QA;  gp_.lda[4]=384; gp_.ldb[4]=192; gp_.ldc[4]=768;  gp_.Nc[4]=768;  gp_.K[4]=192;
  gp_.A[5]=SBF; gp_.BT[5]=TFNKVT; gp_.bias[5]=nullptr; gp_.C[5]=KVA; gp_.lda[5]=384; gp_.ldb[5]=192; gp_.ldc[5]=1536; gp_.Nc[5]=1536; gp_.K[5]=192;
  gp_.xoff[0]=0; gp_.xoff[1]=12; gp_.xoff[2]=36; gp_.xoff[3]=39; gp_.xoff[4]=46; gp_.xoff[5]=58; gp_.xoff[6]=82; gp_.xoff[7]=82;
  gp_.nseg = 6;
  gemm_multi<<<dim3(82, 12), 256, 0, stream>>>(gp_);

  prep_qkv<<<768, 256, 0, stream>>>(s, QR, KVR, QP, KVP, QA, KVA,
                                    rot, trans, head_w, tfnq_wv, tfnkv_wv, ISA,
                                    QCAT, KCAT, RQ, RK, VCATN);
  vcat_t<<<dim3(12, 12), 256, 0, stream>>>(VCATN, VCATT);

  // fused logits + softmax
  logits_soft<<<dim3(48, 12), 256, 0, stream>>>(QCAT, KCAT, BBUF, RQ, RK, mask, ABF);

  // weighted sums
  attn_ov_mfma<<<dim3(48, 12), 256, 0, stream>>>(ABF, VCATT, RESF, ATOMF, OPTRAW);
  attn_pair_mfma<<<768, 256, 0, stream>>>(ABF, PZT, RESF, ATOMF);

  // finalize + merged output GEMMs + select
  finalize_k<<<768, 256, 0, stream>>>(OPTRAW, rot, trans, tfno_wv, RESF, ATOMF, AVEC);
  GM go_;
  go_.A[0]=RESF;  go_.BT[0]=WOUTT; go_.bias[0]=bout;    go_.C[0]=RESOUT; go_.lda[0]=1536; go_.ldb[0]=1536; go_.ldc[0]=384; go_.Nc[0]=384; go_.K[0]=1536;
  go_.A[1]=ATOMF; go_.BT[1]=TFNOT; go_.bias[1]=nullptr; go_.C[1]=ATOMSC; go_.lda[1]=1248; go_.ldb[1]=1248; go_.ldc[1]=192; go_.Nc[1]=192; go_.K[1]=1248;
  for (int i = 2; i < 6; ++i) { go_.A[i]=nullptr; go_.BT[i]=nullptr; go_.bias[i]=nullptr; go_.C[i]=nullptr;
                                go_.lda[i]=0; go_.ldb[i]=0; go_.ldc[i]=0; go_.Nc[i]=0; go_.K[i]=0; }
  go_.xoff[0]=0; go_.xoff[1]=6; go_.xoff[2]=9; go_.xoff[3]=9; go_.xoff[4]=9; go_.xoff[5]=9; go_.xoff[6]=9; go_.xoff[7]=9;
  go_.nseg = 2;
  gemm_multi<<<dim3(9, 12), 256, 0, stream>>>(go_);
  select_k<<<1152, 256, 0, stream>>>(RESOUT, ATOMSC, AVEC, ISA, (float*)d_out);
}

// Round 4
// 189.221 us; speedup vs baseline: 4.1511x; 1.4769x over previous
//
#include <hip/hip_runtime.h>
#include <hip/hip_bf16.h>

static constexpr int NN = 768;

typedef short v8bf __attribute__((ext_vector_type(8)));   // 8 bf16 (4 VGPRs)
typedef float v4f  __attribute__((ext_vector_type(4)));
typedef unsigned short ushort_t;

__device__ __forceinline__ unsigned short f2bf(float f) {
  unsigned u = __float_as_uint(f);
  u += 0x7fffu + ((u >> 16) & 1u);          // RNE
  return (unsigned short)(u >> 16);
}
__device__ __forceinline__ float bf2f(unsigned short s) {
  return __uint_as_float(((unsigned)s) << 16);
}

// -------- workspace layout (float units; all multiples of 64) --------
static constexpr size_t OFF_ISA    = 0;          // 1024 ints
static constexpr size_t OFF_WCT    = 1024;       // 48x128 bf16
static constexpr size_t OFF_BCAT   = 4096;       // 48 f32
static constexpr size_t OFF_SBF    = 4160;       // 768x384 bf16
static constexpr size_t OFF_WQT    = 151616;     // 768x384 bf16
static constexpr size_t OFF_WKVT   = 299072;     // 1536x384 bf16
static constexpr size_t OFF_WQPT   = 593984;     // 192x384 bf16 (144 used)
static constexpr size_t OFF_WKVPT  = 630848;     // 448x384 bf16 (432 used)
static constexpr size_t OFF_TFNQT  = 716864;     // 768x256 bf16 (K=192 + zero pad)
static constexpr size_t OFF_TFNKVT = 815168;     // 1536x256 bf16
static constexpr size_t OFF_WOUTT  = 1011776;    // 384x1536 bf16
static constexpr size_t OFF_TFNOT  = 1306688;    // 192x1280 bf16 (K=1248 + zero pad)
static constexpr size_t OFF_QR     = 1429568;    // 768x768 bf16
static constexpr size_t OFF_KVR    = 1724480;    // 768x1536 bf16
static constexpr size_t OFF_QP     = 2314304;    // 768x144 f32
static constexpr size_t OFF_KVP    = 2424896;    // 768x432 f32
static constexpr size_t OFF_QA     = 2756672;    // 768x768 bf16
static constexpr size_t OFF_KVA    = 3051584;    // 768x1536 bf16
static constexpr size_t OFF_QCAT   = 3641408;    // 768x12x96 bf16
static constexpr size_t OFF_KCAT   = 4083776;    // 768x12x96 bf16
static constexpr size_t OFF_RQ     = 4526144;    // 12x768 f32
static constexpr size_t OFF_RK     = 4535360;    // 12x768 f32
static constexpr size_t OFF_VCATN  = 4544576;    // 768x12x96 bf16
static constexpr size_t OFF_VCATT  = 4986944;    // 12x96x768 bf16
static constexpr size_t OFF_BB     = 5429312;    // 12x768x768 bf16
static constexpr size_t OFF_PZT    = 8968256;    // 768x32x768 bf16
static constexpr size_t OFF_ABF    = 18405440;   // 12x768x768 bf16
static constexpr size_t OFF_OPTRAW = 21944384;   // 768x288 f32
static constexpr size_t OFF_RESF   = 22165568;   // 768x1536 bf16
static constexpr size_t OFF_ATOMF  = 22755392;   // 768x1280 bf16 (1248 used)

// ================= prep0: detect + wcat + all weight converts =================
__device__ void transpose_cv(const float* __restrict__ src, unsigned short* __restrict__ dst,
                             int K, int Kp, int N, int ky, int nx) {
  __shared__ float tl[32][33];
  const int k0 = ky * 32, n0 = nx * 32;
  const int tx = threadIdx.x & 31, ty = threadIdx.x >> 5;
  for (int it = 0; it < 4; ++it) {
    int r = ty + it * 8;
    float v = 0.f;
    if (k0 + r < K && n0 + tx < N) v = src[(long long)(k0 + r) * N + n0 + tx];
    tl[r][tx] = v;
  }
  __syncthreads();
  for (int it = 0; it < 4; ++it) {
    int r = ty + it * 8;
    if (n0 + r < N && k0 + tx < Kp)
      dst[(long long)(n0 + r) * Kp + k0 + tx] = f2bf(tl[tx][r]);
  }
}

__global__ __launch_bounds__(256) void prep0(
    float* wsf, const float* s, const float* wq, const float* wkv,
    const float* wqp, const float* wkvp, const float* tfnq_ws,
    const float* tfnkv_ws, const float* wout, const float* tfno_ws,
    const float* wb, const float* wdz, const float* bb, const float* bdz,
    const unsigned int* isa_raw)
{
  const int bx = blockIdx.x, t = threadIdx.x;
  if (bx < 288)       { int g = bx;        transpose_cv(wq,      (unsigned short*)(wsf+OFF_WQT),    384, 384, 768,  g/24, g%24); return; }
  else if (bx < 864)  { int g = bx-288;    transpose_cv(wkv,     (unsigned short*)(wsf+OFF_WKVT),   384, 384, 1536, g/48, g%48); return; }
  else if (bx < 924)  { int g = bx-864;    transpose_cv(wqp,     (unsigned short*)(wsf+OFF_WQPT),   384, 384, 144,  g/5,  g%5);  return; }
  else if (bx < 1092) { int g = bx-924;    transpose_cv(wkvp,    (unsigned short*)(wsf+OFF_WKVPT),  384, 384, 432,  g/14, g%14); return; }
  else if (bx < 1284) { int g = bx-1092;   transpose_cv(tfnq_ws, (unsigned short*)(wsf+OFF_TFNQT),  192, 256, 768,  g/24, g%24); return; }
  else if (bx < 1668) { int g = bx-1284;   transpose_cv(tfnkv_ws,(unsigned short*)(wsf+OFF_TFNKVT), 192, 256, 1536, g/48, g%48); return; }
  else if (bx < 2244) { int g = bx-1668;   transpose_cv(wout,    (unsigned short*)(wsf+OFF_WOUTT),  1536,1536,384,  g/12, g%12); return; }
  else if (bx < 2484) { int g = bx-2244;   transpose_cv(tfno_ws, (unsigned short*)(wsf+OFF_TFNOT),  1248,1280,192,  g/6,  g%6);  return; }
  else if (bx < 2772) {
    // s -> bf16 (294912 elems = 288 * 1024)
    long long base = (long long)(bx - 2484) * 1024 + t * 4;
    float4 v = *(const float4*)(s + base);
    unsigned short tmp[4] = {f2bf(v.x), f2bf(v.y), f2bf(v.z), f2bf(v.w)};
    *(uint2*)((unsigned short*)(wsf + OFF_SBF) + base) = *(uint2*)tmp;
    return;
  } else if (bx < 2773) {
    // detect is_atom dtype + build ISA
    __shared__ int notint, notfloat;
    int* ISA = (int*)(wsf + OFF_ISA);
    if (t == 0) { notint = 0; notfloat = 0; }
    __syncthreads();
    if (t < 192) {
      unsigned v = isa_raw[t];
      if (v > 1u) atomicOr(&notint, 1);
      if (v != 0u && v != 0x3F800000u) atomicOr(&notfloat, 1);
    }
    __syncthreads();
    const int mode = (!notint) ? 0 : ((!notfloat) ? 1 : 2);
    for (int n = t; n < NN; n += 256) {
      int val;
      if (mode == 2) val = (((const unsigned char*)isa_raw)[n] != 0);
      else           val = (isa_raw[n] != 0u);
      ISA[n] = val;
    }
    return;
  } else {
    // WCT (48x128, scaled, transposed) + bcat
    const float rs3 = 0.57735026918962576f;
    unsigned short* WCT = (unsigned short*)(wsf + OFF_WCT);
    float* bcat = wsf + OFF_BCAT;
    int idx = (bx - 2773) * 256 + t;
    if (idx < 48 * 128) {
      int o = idx >> 7, k = idx & 127;
      float v = 0.f;
      if (o < 12) v = rs3 * wb[k * 12 + o];
      else if (o < 44) v = wdz[k * 32 + (o - 12)];
      WCT[o * 128 + k] = f2bf(v);
    }
    if (bx == 2773 && t < 48)
      bcat[t] = (t < 12) ? rs3 * bb[t] : (t < 44 ? bdz[t - 12] : 0.f);
  }
}

// ================= gemm16: 16 rows x 64 cols, 4-wave split-K =================
// mode 0: f32 C; 1: bf16 C; 2: f32->out if !ISA[r]; 3: f32->out if ISA[r]
__device__ __forceinline__ void gemm16(
    char* lds, const unsigned short* __restrict__ A, int lda,
    const unsigned short* __restrict__ BT, int ldb, int KQ,
    const float* __restrict__ bias, int mode,
    float* Cf, unsigned short* Cb, int ldc, int Nc, int colb, int row0,
    const int* __restrict__ ISA, float* outp)
{
  v4f (*PS)[4][64] = (v4f (*)[4][64])lds;
  const int t = threadIdx.x, w = t >> 6, l = t & 63, l15 = l & 15, lg = l >> 4;
  const int rowA = row0 + l15;
  v4f acc[4] = {};
  const unsigned short* ap = A + (long long)rowA * lda + lg * 8;
  const int kend = (w + 1) * KQ;
  for (int k0 = w * KQ; k0 < kend; k0 += 32) {
    v8bf av = *(const v8bf*)(ap + k0);
#pragma unroll
    for (int cf = 0; cf < 4; ++cf) {
      v8bf bv = *(const v8bf*)(BT + (long long)(colb + cf * 16 + l15) * ldb + k0 + lg * 8);
      acc[cf] = __builtin_amdgcn_mfma_f32_16x16x32_bf16(av, bv, acc[cf], 0, 0, 0);
    }
  }
#pragma unroll
  for (int cf = 0; cf < 4; ++cf) PS[w][cf][l] = acc[cf];
  __syncthreads();
  const int cf = w;
  v4f sv = PS[0][cf][l] + PS[1][cf][l] + PS[2][cf][l] + PS[3][cf][l];
  const int c = colb + cf * 16 + l15;
  if (c < Nc) {
    float bvs = bias ? bias[c] : 0.f;
#pragma unroll
    for (int i = 0; i < 4; ++i) {
      int r = row0 + lg * 4 + i;
      float v = sv[i] + bvs;
      if (mode == 0)      Cf[(long long)r * ldc + c] = v;
      else if (mode == 1) Cb[(long long)r * ldc + c] = f2bf(v);
      else if (mode == 2) { if (!ISA[r]) outp[r * 384 + c] = v; }
      else                { if ( ISA[r]) outp[r * 384 + c] = v; }
    }
  }
}

// ================= mega1: zpass (4608) || projection GEMMs (3936) =================
__global__ __launch_bounds__(256) void mega1(
    float* wsf, const float* __restrict__ z,
    const float* bq, const float* bkv, const float* bqp, const float* bkvp)
{
  __shared__ __align__(16) char lds[34816];
  const int t = threadIdx.x;
  if (blockIdx.x < 4608) {
    // ---- zpass: Bb bf16 + PZT bf16 ----
    unsigned short* Abf = (unsigned short*)lds;
    float* Sout = (float*)lds;
    const unsigned short* WCT = (const unsigned short*)(wsf + OFF_WCT);
    const float* bcat = wsf + OFF_BCAT;
    unsigned short* Bb  = (unsigned short*)(wsf + OFF_BB);
    unsigned short* PZT = (unsigned short*)(wsf + OFF_PZT);
    const long long row0 = (long long)blockIdx.x * 128;
    for (int i = 0; i < 16; ++i) {
      int fi = (i * 256 + t) * 4;
      float4 v = *(const float4*)(z + row0 * 128 + fi);
      int r = fi >> 7, c = fi & 127;
      unsigned short tmp[4] = {f2bf(v.x), f2bf(v.y), f2bf(v.z), f2bf(v.w)};
      *(uint2*)(Abf + r * 136 + c) = *(uint2*)tmp;
    }
    __syncthreads();
    const int w = t >> 6, l = t & 63, l15 = l & 15, lg = l >> 4;
    v4f acc[2][3] = {};
    for (int ks = 0; ks < 4; ++ks) {
      v8bf bvv[3];
#pragma unroll
      for (int cf = 0; cf < 3; ++cf)
        bvv[cf] = *(const v8bf*)(WCT + (cf * 16 + l15) * 128 + ks * 32 + lg * 8);
#pragma unroll
      for (int rf = 0; rf < 2; ++rf) {
        v8bf av = *(const v8bf*)(Abf + (w * 32 + rf * 16 + l15) * 136 + ks * 32 + lg * 8);
#pragma unroll
        for (int cf = 0; cf < 3; ++cf)
          acc[rf][cf] = __builtin_amdgcn_mfma_f32_16x16x32_bf16(av, bvv[cf], acc[rf][cf], 0, 0, 0);
      }
    }
    __syncthreads();
#pragma unroll
    for (int rf = 0; rf < 2; ++rf)
#pragma unroll
      for (int cf = 0; cf < 3; ++cf) {
        int o = cf * 16 + l15;
#pragma unroll
        for (int i = 0; i < 4; ++i) {
          int m = w * 32 + rf * 16 + lg * 4 + i;
          Sout[o * 132 + m] = acc[rf][cf][i];
        }
      }
    __syncthreads();
    const int n = blockIdx.x / 6;
    const int m0 = (blockIdx.x % 6) * 128;
    for (int idx = t; idx < 44 * 8; idx += 256) {
      int o = idx >> 3, seg = idx & 7;
      float bias = bcat[o];
      unsigned short tmp[16];
#pragma unroll
      for (int j = 0; j < 16; ++j) tmp[j] = f2bf(Sout[o * 132 + seg * 16 + j] + bias);
      unsigned short* gp;
      if (o < 12) gp = Bb + ((long long)o * 768 + n) * 768 + m0 + seg * 16;
      else        gp = PZT + ((long long)n * 32 + (o - 12)) * 768 + m0 + seg * 16;
      *(uint4*)gp = *(uint4*)tmp;
      *(uint4*)(gp + 8) = *(uint4*)(tmp + 8);
    }
    return;
  }
  // ---- projection GEMMs ----
  const int g = blockIdx.x - 4608;
  const int bt = g / 82, xt = g % 82;
  const unsigned short* SBF = (const unsigned short*)(wsf + OFF_SBF);
  const unsigned short* BT; const float* bias; int ldb, KQ, mode, ldc, Nc, colb;
  float* Cf = nullptr; unsigned short* Cb = nullptr;
  if (xt < 12)      { BT=(const unsigned short*)(wsf+OFF_WQT);    bias=bq;     ldb=384; KQ=96; Cb=(unsigned short*)(wsf+OFF_QR);  ldc=768;  Nc=768;  colb=xt*64;      mode=1; }
  else if (xt < 36) { BT=(const unsigned short*)(wsf+OFF_WKVT);   bias=bkv;    ldb=384; KQ=96; Cb=(unsigned short*)(wsf+OFF_KVR); ldc=1536; Nc=1536; colb=(xt-12)*64; mode=1; }
  else if (xt < 39) { BT=(const unsigned short*)(wsf+OFF_WQPT);   bias=bqp;    ldb=384; KQ=96; Cf=wsf+OFF_QP;                     ldc=144;  Nc=144;  colb=(xt-36)*64; mode=0; }
  else if (xt < 46) { BT=(const unsigned short*)(wsf+OFF_WKVPT);  bias=bkvp;   ldb=384; KQ=96; Cf=wsf+OFF_KVP;                    ldc=432;  Nc=432;  colb=(xt-39)*64; mode=0; }
  else if (xt < 58) { BT=(const unsigned short*)(wsf+OFF_TFNQT);  bias=nullptr;ldb=256; KQ=64; Cb=(unsigned short*)(wsf+OFF_QA);  ldc=768;  Nc=768;  colb=(xt-46)*64; mode=1; }
  else              { BT=(const unsigned short*)(wsf+OFF_TFNKVT); bias=nullptr;ldb=256; KQ=64; Cb=(unsigned short*)(wsf+OFF_KVA); ldc=1536; Nc=1536; colb=(xt-58)*64; mode=1; }
  gemm16(lds, SBF, 384, BT, ldb, KQ, bias, mode, Cf, Cb, ldc, Nc, colb, bt * 16, nullptr, nullptr);
}

// ================= prep_qkv =================
__global__ __launch_bounds__(256) void prep_qkv(
    float* wsf, const float* __restrict__ s,
    const float* __restrict__ rot, const float* __restrict__ trans,
    const float* __restrict__ head_w,
    const float* __restrict__ tfnq_wv, const float* __restrict__ tfnkv_wv)
{
  const int n = blockIdx.x, t = threadIdx.x;
  const int* ISA = (const int*)(wsf + OFF_ISA);
  const unsigned short* QRb  = (const unsigned short*)(wsf + OFF_QR);
  const unsigned short* KVRb = (const unsigned short*)(wsf + OFF_KVR);
  const unsigned short* QAb  = (const unsigned short*)(wsf + OFF_QA);
  const unsigned short* KVAb = (const unsigned short*)(wsf + OFF_KVA);
  const float* QP  = wsf + OFF_QP;
  const float* KVP = wsf + OFF_KVP;
  unsigned short* Qcat  = (unsigned short*)(wsf + OFF_QCAT);
  unsigned short* Kcat  = (unsigned short*)(wsf + OFF_KCAT);
  unsigned short* Vcatn = (unsigned short*)(wsf + OFF_VCATN);
  float* rq = wsf + OFF_RQ;
  float* rk = wsf + OFF_RK;
  const bool isa = ISA[n] != 0;
  __shared__ float R[9], T[3], shw[12], sv[192];
  __shared__ float qs[768], ks[768], vs[768], qp[144], kp[144], vp[288];
  if (t < 9) R[t] = rot[n * 9 + t];
  if (t < 3) T[t] = trans[n * 3 + t];
  if (t >= 16 && t < 28)
    shw[t - 16] = log1pf(__expf(head_w[t - 16])) * 0.13608276348795434f;
  if (isa && t >= 32 && t < 224) sv[t - 32] = s[(size_t)n * 384 + 192 + (t - 32)];
  __syncthreads();
  for (int idx = t; idx < 768; idx += 256) {
    int h = idx >> 6, c = idx & 63;
    qs[idx] = bf2f(isa ? QAb[(long long)n * 768 + idx] : QRb[(long long)n * 768 + idx]);
    ks[idx] = bf2f(isa ? KVAb[(long long)n * 1536 + h * 128 + c] : KVRb[(long long)n * 1536 + h * 128 + c]);
    vs[idx] = bf2f(isa ? KVAb[(long long)n * 1536 + h * 128 + 64 + c] : KVRb[(long long)n * 1536 + h * 128 + 64 + c]);
  }
  if (isa) {
    for (int idx = t; idx < 144; idx += 256) {
      int hp = idx / 3, x = idx % 3;
      float a = 0.f;
      for (int i = 0; i < 64; ++i) a += sv[i * 3 + x] * tfnq_wv[i * 48 + hp];
      qp[idx] = a + T[x];
    }
    for (int idx = t; idx < 432; idx += 256) {
      int o = idx / 3, x = idx % 3;
      float a = 0.f;
      for (int i = 0; i < 64; ++i) a += sv[i * 3 + x] * tfnkv_wv[i * 144 + o];
      float v = a + T[x];
      int h = o / 12, pp = o % 12;
      if (pp < 4) kp[(h * 4 + pp) * 3 + x] = v;
      else        vp[(h * 8 + (pp - 4)) * 3 + x] = v;
    }
  } else {
    for (int idx = t; idx < 144; idx += 256) {
      int hp = idx / 3, i = idx % 3;
      qp[idx] = R[i * 3 + 0] * QP[(long long)n * 144 + 0 + hp] +
                R[i * 3 + 1] * QP[(long long)n * 144 + 48 + hp] +
                R[i * 3 + 2] * QP[(long long)n * 144 + 96 + hp] + T[i];
    }
    for (int idx = t; idx < 432; idx += 256) {
      int hp = idx / 3, i = idx % 3;
      float v = R[i * 3 + 0] * KVP[(long long)n * 432 + 0 + hp] +
                R[i * 3 + 1] * KVP[(long long)n * 432 + 144 + hp] +
                R[i * 3 + 2] * KVP[(long long)n * 432 + 288 + hp] + T[i];
      int h = hp / 12, pp = hp % 12;
      if (pp < 4) kp[(h * 4 + pp) * 3 + i] = v;
      else        vp[(h * 8 + (pp - 4)) * 3 + i] = v;
    }
  }
  __syncthreads();
  const float sq = 0.07216878364870322f;  // sqrt(1/192)
  for (int idx = t; idx < 1152; idx += 256) {
    int h = idx / 96, c = idx % 96;
    float qv = (c < 64) ? sq * qs[h * 64 + c] : ((c < 76) ? shw[h] * qp[h * 12 + (c - 64)] : 0.f);
    float kv = (c < 64) ? ks[h * 64 + c]      : ((c < 76) ? kp[h * 12 + (c - 64)] : 0.f);
    float vv = (c < 64) ? vs[h * 64 + c]      : ((c < 88) ? vp[h * 24 + (c - 64)] : 0.f);
    long long base = ((long long)n * 12 + h) * 96 + c;
    Qcat[base] = f2bf(qv);
    Kcat[base] = f2bf(kv);
    Vcatn[base] = f2bf(vv);
  }
  if (t < 24) {
    int h = t >> 1, which = t & 1;
    const float* p = which ? kp : qp;
    float s2 = 0.f;
#pragma unroll
    for (int d = 0; d < 12; ++d) { float x = p[h * 12 + d]; s2 += x * x; }
    float val = 0.5f * shw[h] * s2;
    if (which) rk[h * 768 + n] = val;
    else       rq[h * 768 + n] = val;
  }
}

// ================= mega2: logits+softmax (576) || vcat transpose (144) =================
__global__ __launch_bounds__(256) void mega2(float* wsf, const float* __restrict__ mask) {
  __shared__ __align__(16) char lds[26112];
  const int t = threadIdx.x;
  if (blockIdx.x < 576) {
    const unsigned short* Qcat = (const unsigned short*)(wsf + OFF_QCAT);
    const unsigned short* Kcat = (const unsigned short*)(wsf + OFF_KCAT);
    const unsigned short* Bb   = (const unsigned short*)(wsf + OFF_BB);
    const float* rq = wsf + OFF_RQ;
    const float* rk = wsf + OFF_RK;
    unsigned short* Abf = (unsigned short*)(wsf + OFF_ABF);
    const int h = blockIdx.x / 48, r0 = (blockIdx.x % 48) * 16;
    const int w = t >> 6, l = t & 63, l15 = l & 15, lg = l >> 4;
    unsigned short* SW = (unsigned short*)lds + w * 3200;   // [16][200] per wave
    float* redm = (float*)(lds + 25600);                    // [4][16]
    float* reds = (float*)(lds + 25856);                    // [4][16]
    const int nrow = r0 + l15;
    v8bf aq[3];
#pragma unroll
    for (int ks = 0; ks < 3; ++ks)
      aq[ks] = *(const v8bf*)(Qcat + ((long long)nrow * 12 + h) * 96 + ks * 32 + lg * 8);
    v4f acc[12] = {};
#pragma unroll
    for (int cf = 0; cf < 12; ++cf) {
      int m = w * 192 + cf * 16 + l15;
      const unsigned short* kb = Kcat + ((long long)m * 12 + h) * 96 + lg * 8;
#pragma unroll
      for (int ks = 0; ks < 3; ++ks) {
        v8bf bv = *(const v8bf*)(kb + ks * 32);
        acc[cf] = __builtin_amdgcn_mfma_f32_16x16x32_bf16(aq[ks], bv, acc[cf], 0, 0, 0);
      }
    }
    // stage Bb tile (16 rows x 192 cols) into SW, coalesced
#pragma unroll
    for (int it = 0; it < 6; ++it) {
      int chunk = it * 64 + l;
      int row = chunk / 24, cc = (chunk % 24) * 8;
      *(uint4*)(SW + row * 200 + cc) =
          *(const uint4*)(Bb + ((long long)(h * 768 + r0 + row)) * 768 + w * 192 + cc);
    }
    __syncthreads();
    float rkm[12], mkm[12];
#pragma unroll
    for (int cf = 0; cf < 12; ++cf) {
      int m = w * 192 + cf * 16 + l15;
      rkm[cf] = rk[h * 768 + m];
      mkm[cf] = mask[m];
    }
    float rqn[4], mkn[4], mymax[4];
#pragma unroll
    for (int i = 0; i < 4; ++i) {
      int gn = r0 + lg * 4 + i;
      rqn[i] = rq[h * 768 + gn];
      mkn[i] = mask[gn];
      mymax[i] = -3.0e38f;
    }
#pragma unroll
    for (int cf = 0; cf < 12; ++cf)
#pragma unroll
      for (int i = 0; i < 4; ++i) {
        float v = acc[cf][i] + bf2f(SW[(lg * 4 + i) * 200 + cf * 16 + l15])
                - rqn[i] - rkm[cf] + 100000.0f * (mkn[i] * mkm[cf] - 1.0f);
        acc[cf][i] = v;
        mymax[i] = fmaxf(mymax[i], v);
      }
#pragma unroll
    for (int off = 1; off < 16; off <<= 1)
#pragma unroll
      for (int i = 0; i < 4; ++i) mymax[i] = fmaxf(mymax[i], __shfl_xor(mymax[i], off, 64));
    if (l15 == 0) {
#pragma unroll
      for (int i = 0; i < 4; ++i) redm[w * 16 + lg * 4 + i] = mymax[i];
    }
    __syncthreads();
    float mx[4], mysum[4];
#pragma unroll
    for (int i = 0; i < 4; ++i) {
      int rl = lg * 4 + i;
      mx[i] = fmaxf(fmaxf(redm[rl], redm[16 + rl]), fmaxf(redm[32 + rl], redm[48 + rl]));
      mysum[i] = 0.f;
    }
#pragma unroll
    for (int cf = 0; cf < 12; ++cf)
#pragma unroll
      for (int i = 0; i < 4; ++i) {
        float e = __expf(acc[cf][i] - mx[i]);
        acc[cf][i] = e;
        mysum[i] += e;
      }
#pragma unroll
    for (int off = 1; off < 16; off <<= 1)
#pragma unroll
      for (int i = 0; i < 4; ++i) mysum[i] += __shfl_xor(mysum[i], off, 64);
    if (l15 == 0) {
#pragma unroll
      for (int i = 0; i < 4; ++i) reds[w * 16 + lg * 4 + i] = mysum[i];
    }
    __syncthreads();
    float inv[4];
#pragma unroll
    for (int i = 0; i < 4; ++i) {
      int rl = lg * 4 + i;
      inv[i] = 1.0f / (reds[rl] + reds[16 + rl] + reds[32 + rl] + reds[48 + rl]);
    }
#pragma unroll
    for (int cf = 0; cf < 12; ++cf)
#pragma unroll
      for (int i = 0; i < 4; ++i)
        SW[(lg * 4 + i) * 200 + cf * 16 + l15] = f2bf(acc[cf][i] * inv[i]);
    __syncthreads();
#pragma unroll
    for (int it = 0; it < 6; ++it) {
      int chunk = it * 64 + l;
      int row = chunk / 24, cc = (chunk % 24) * 8;
      *(uint4*)(Abf + ((long long)(h * 768 + r0 + row)) * 768 + w * 192 + cc) =
          *(const uint4*)(SW + row * 200 + cc);
    }
    return;
  }
  // ---- vcat transpose: [n][h][96] bf16 -> [h][96][768] bf16 ----
  {
    const unsigned short* Vn = (const unsigned short*)(wsf + OFF_VCATN);
    unsigned short* Vt = (unsigned short*)(wsf + OFF_VCATT);
    const int g = blockIdx.x - 576;
    const int h = g / 12, n0 = (g % 12) * 64;
    unsigned short (*tl)[104] = (unsigned short (*)[104])lds;
    for (int i4 = t; i4 < 768; i4 += 256) {
      int r = i4 / 12, cseg = (i4 % 12) * 8;
      *(uint4*)(&tl[r][cseg]) = *(const uint4*)(Vn + ((long long)(n0 + r) * 12 + h) * 96 + cseg);
    }
    __syncthreads();
    for (int i4 = t; i4 < 768; i4 += 256) {
      int c = i4 >> 3, seg = i4 & 7;
      unsigned short tmp[8];
#pragma unroll
      for (int j = 0; j < 8; ++j) tmp[j] = tl[seg * 8 + j][c];
      *(uint4*)(Vt + ((long long)h * 96 + c) * 768 + n0 + seg * 8) = *(uint4*)tmp;
    }
  }
}

// ================= mega3: attn_ov (576) || attn_pair (768) =================
__global__ __launch_bounds__(256) void mega3(float* wsf) {
  __shared__ __align__(16) char lds[24576];
  const int t = threadIdx.x, w = t >> 6, l = t & 63, l15 = l & 15, lg = l >> 4;
  const unsigned short* Abf = (const unsigned short*)(wsf + OFF_ABF);
  unsigned short* RESF  = (unsigned short*)(wsf + OFF_RESF);
  unsigned short* ATOMF = (unsigned short*)(wsf + OFF_ATOMF);
  if (blockIdx.x < 576) {
    const unsigned short* VcatT = (const unsigned short*)(wsf + OFF_VCATT);
    float* OPTRAW = wsf + OFF_OPTRAW;
    v4f (*PS)[64] = (v4f (*)[64])lds;    // [24][64]
    const int h = blockIdx.x / 48, nt = blockIdx.x % 48;
    const int nrow = nt * 16 + l15;
    const unsigned short* arow = Abf + ((long long)h * 768 + nrow) * 768 + lg * 8;
    const unsigned short* vbase = VcatT + (long long)h * 96 * 768 + lg * 8;
    v4f acc[6] = {};
    for (int k0 = w * 192; k0 < w * 192 + 192; k0 += 32) {
      v8bf av = *(const v8bf*)(arow + k0);
#pragma unroll
      for (int cf = 0; cf < 6; ++cf) {
        v8bf bv = *(const v8bf*)(vbase + (long long)(cf * 16 + l15) * 768 + k0);
        acc[cf] = __builtin_amdgcn_mfma_f32_16x16x32_bf16(av, bv, acc[cf], 0, 0, 0);
      }
    }
#pragma unroll
    for (int cf = 0; cf < 6; ++cf) PS[w * 6 + cf][l] = acc[cf];
    __syncthreads();
    for (int cf = w; cf < 6; cf += 4) {
      v4f sv = PS[cf][l] + PS[6 + cf][l] + PS[12 + cf][l] + PS[18 + cf][l];
      int c = cf * 16 + l15;
      int rb = nt * 16 + lg * 4;
#pragma unroll
      for (int i = 0; i < 4; ++i) {
        int n = rb + i;
        float v = sv[i];
        if (c < 64) {
          unsigned short b = f2bf(v);
          RESF[(long long)n * 1536 + h * 64 + c] = b;
          ATOMF[(long long)n * 1280 + h * 64 + c] = b;
        } else if (c < 88) {
          OPTRAW[(long long)n * 288 + h * 24 + (c - 64)] = v;
        }
      }
    }
    return;
  }
  // ---- attn_pair ----
  {
    const unsigned short* PZT = (const unsigned short*)(wsf + OFF_PZT);
    v4f (*PS)[64] = (v4f (*)[64])lds;    // [8][64]
    const int n = blockIdx.x - 576;
    const int hh = (l15 < 12) ? l15 : 0;
    const unsigned short* arow = Abf + ((long long)hh * 768 + n) * 768 + lg * 8;
    const unsigned short* pz = PZT + (long long)n * 32 * 768 + lg * 8;
    v4f acc[2] = {};
    for (int k0 = w * 192; k0 < w * 192 + 192; k0 += 32) {
      v8bf av = *(const v8bf*)(arow + k0);
#pragma unroll
      for (int cf = 0; cf < 2; ++cf) {
        v8bf bv = *(const v8bf*)(pz + (long long)(cf * 16 + l15) * 768 + k0);
        acc[cf] = __builtin_amdgcn_mfma_f32_16x16x32_bf16(av, bv, acc[cf], 0, 0, 0);
      }
    }
    PS[w * 2 + 0][l] = acc[0];
    PS[w * 2 + 1][l] = acc[1];
    __syncthreads();
    if (t < 128) {
      int cf = t >> 6, ll = t & 63;
      v4f sv = PS[cf][ll] + PS[2 + cf][ll] + PS[4 + cf][ll] + PS[6 + cf][ll];
      int zc = cf * 16 + (ll & 15);
#pragma unroll
      for (int i = 0; i < 4; ++i) {
        int hd = (ll >> 4) * 4 + i;
        if (hd < 12) {
          unsigned short b = f2bf(sv[i]);
          RESF[(long long)n * 1536 + 1152 + hd * 32 + zc] = b;
          ATOMF[(long long)n * 1280 + 864 + hd * 32 + zc] = b;
        }
      }
    }
  }
}

// ================= finalize: inverse rigid, norms, feats, atom_vec -> out =================
__global__ __launch_bounds__(256) void finalize_k(
    float* wsf, const float* __restrict__ rot, const float* __restrict__ trans,
    const float* __restrict__ tfno_wv, float* __restrict__ out)
{
  const int n = blockIdx.x, t = threadIdx.x;
  const float* OPTRAW = wsf + OFF_OPTRAW;
  unsigned short* RESF  = (unsigned short*)(wsf + OFF_RESF);
  unsigned short* ATOMF = (unsigned short*)(wsf + OFF_ATOMF);
  const int* ISA = (const int*)(wsf + OFF_ISA);
  const bool isa = ISA[n] != 0;
  __shared__ float R[9], T[3], opt2[96][3], norml[96];
  if (t < 9) R[t] = rot[(size_t)n * 9 + t];
  if (t < 3) T[t] = trans[(size_t)n * 3 + t];
  __syncthreads();
  for (int idx = t; idx < 288; idx += 256) {
    int hp = idx / 3, i = idx % 3;
    float x = OPTRAW[(size_t)n * 288 + hp * 3 + 0] - T[0];
    float y = OPTRAW[(size_t)n * 288 + hp * 3 + 1] - T[1];
    float z = OPTRAW[(size_t)n * 288 + hp * 3 + 2] - T[2];
    opt2[hp][i] = R[0 + i] * x + R[3 + i] * y + R[6 + i] * z;  // rot^T
  }
  __syncthreads();
  if (t < 96)
    norml[t] = sqrtf(opt2[t][0] * opt2[t][0] + opt2[t][1] * opt2[t][1] +
                     opt2[t][2] * opt2[t][2] + 1e-8f);
  __syncthreads();
  const long long rb = (long long)n * 1536;
  const long long ab = (long long)n * 1280;
  for (int idx = t; idx < 288; idx += 256) {
    int x = idx / 96, hp = idx % 96;
    RESF[rb + 768 + idx] = f2bf(opt2[hp][x]);
  }
  for (int idx = t; idx < 96; idx += 256) {
    unsigned short b = f2bf(norml[idx]);
    RESF[rb + 1056 + idx] = b;
    ATOMF[ab + 768 + idx] = b;
  }
  if (isa) {
    for (int idx = t; idx < 192; idx += 256) {
      int o = idx / 3, x = idx % 3;
      float a = 0.f;
      for (int p = 0; p < 96; ++p) a += opt2[p][x] * tfno_wv[p * 64 + o];
      out[(size_t)n * 384 + 192 + idx] = a;
    }
  }
}

// ================= out GEMMs (predicated writes into d_out) =================
__global__ __launch_bounds__(256) void outg(float* wsf, const float* __restrict__ bout,
                                            float* __restrict__ out) {
  __shared__ __align__(16) char lds[16384];
  const int g = blockIdx.x;
  const int bt = g / 9, xt = g % 9;
  const int* ISA = (const int*)(wsf + OFF_ISA);
  if (xt < 6)
    gemm16(lds, (const unsigned short*)(wsf + OFF_RESF), 1536,
           (const unsigned short*)(wsf + OFF_WOUTT), 1536, 384, bout, 2,
           nullptr, nullptr, 0, 384, xt * 64, bt * 16, ISA, out);
  else
    gemm16(lds, (const unsigned short*)(wsf + OFF_ATOMF), 1280,
           (const unsigned short*)(wsf + OFF_TFNOT), 1280, 320, nullptr, 3,
           nullptr, nullptr, 0, 192, (xt - 6) * 64, bt * 16, ISA, out);
}

extern "C" void kernel_launch(void* const* d_in, const int* in_sizes, int n_in,
                              void* d_out, int out_size, void* d_ws, size_t ws_size,
                              hipStream_t stream) {
  (void)in_sizes; (void)n_in; (void)out_size; (void)ws_size;
  const float* s      = (const float*)d_in[0];
  const float* z      = (const float*)d_in[1];
  const float* rot    = (const float*)d_in[2];
  const float* trans  = (const float*)d_in[3];
  const float* mask   = (const float*)d_in[4];
  const float* wq     = (const float*)d_in[6];
  const float* bq     = (const float*)d_in[7];
  const float* wkv    = (const float*)d_in[8];
  const float* bkv    = (const float*)d_in[9];
  const float* wqp    = (const float*)d_in[10];
  const float* bqp    = (const float*)d_in[11];
  const float* wkvp   = (const float*)d_in[12];
  const float* bkvp   = (const float*)d_in[13];
  const float* wb     = (const float*)d_in[14];
  const float* bb     = (const float*)d_in[15];
  const float* wdz    = (const float*)d_in[16];
  const float* bdz    = (const float*)d_in[17];
  const float* head_w = (const float*)d_in[18];
  const float* wout   = (const float*)d_in[19];
  const float* bout   = (const float*)d_in[20];
  const float* tfnq_ws  = (const float*)d_in[21];
  const float* tfnq_wv  = (const float*)d_in[22];
  const float* tfnkv_ws = (const float*)d_in[23];
  const float* tfnkv_wv = (const float*)d_in[24];
  const float* tfno_ws  = (const float*)d_in[25];
  const float* tfno_wv  = (const float*)d_in[26];

  float* wsf = (float*)d_ws;

  prep0<<<2797, 256, 0, stream>>>(wsf, s, wq, wkv, wqp, wkvp, tfnq_ws, tfnkv_ws,
                                  wout, tfno_ws, wb, wdz, bb, bdz,
                                  (const unsigned int*)d_in[5]);
  mega1<<<8544, 256, 0, stream>>>(wsf, z, bq, bkv, bqp, bkvp);
  prep_qkv<<<768, 256, 0, stream>>>(wsf, s, rot, trans, head_w, tfnq_wv, tfnkv_wv);
  mega2<<<720, 256, 0, stream>>>(wsf, mask);
  mega3<<<1344, 256, 0, stream>>>(wsf);
  finalize_k<<<768, 256, 0, stream>>>(wsf, rot, trans, tfno_wv, (float*)d_out);
  outg<<<432, 256, 0, stream>>>(wsf, bout, (float*)d_out);
}

// Round 5
// 186.087 us; speedup vs baseline: 4.2210x; 1.0168x over previous
//
#include <hip/hip_runtime.h>
#include <hip/hip_bf16.h>

static constexpr int NN = 768;

typedef short v8bf __attribute__((ext_vector_type(8)));   // 8 bf16 (4 VGPRs)
typedef float v4f  __attribute__((ext_vector_type(4)));

__device__ __forceinline__ unsigned short f2bf(float f) {
  unsigned u = __float_as_uint(f);
  u += 0x7fffu + ((u >> 16) & 1u);          // RNE
  return (unsigned short)(u >> 16);
}
__device__ __forceinline__ float bf2f(unsigned short s) {
  return __uint_as_float(((unsigned)s) << 16);
}

// -------- workspace layout (float units; all multiples of 64) --------
static constexpr size_t OFF_ISA    = 0;          // 1024 ints
static constexpr size_t OFF_WCT    = 1024;       // 48x128 bf16
static constexpr size_t OFF_BCAT   = 4096;       // 48 f32
static constexpr size_t OFF_SBF    = 4160;       // 768x384 bf16
static constexpr size_t OFF_WQT    = 151616;     // 768x384 bf16
static constexpr size_t OFF_WKVT   = 299072;     // 1536x384 bf16
static constexpr size_t OFF_WQPT   = 593984;     // 192x384 bf16 (144 used)
static constexpr size_t OFF_WKVPT  = 630848;     // 448x384 bf16 (432 used)
static constexpr size_t OFF_TFNQT  = 716864;     // 768x256 bf16 (K=192 + zero pad)
static constexpr size_t OFF_TFNKVT = 815168;     // 1536x256 bf16
static constexpr size_t OFF_WOUTT  = 1011776;    // 384x1536 bf16
static constexpr size_t OFF_TFNOT  = 1306688;    // 192x1280 bf16 (K=1248 + zero pad)
static constexpr size_t OFF_QR     = 1429568;    // 768x768 bf16
static constexpr size_t OFF_KVR    = 1724480;    // 768x1536 bf16
static constexpr size_t OFF_QP     = 2314304;    // 768x144 f32
static constexpr size_t OFF_KVP    = 2424896;    // 768x432 f32
static constexpr size_t OFF_QA     = 2756672;    // 768x768 bf16
static constexpr size_t OFF_KVA    = 3051584;    // 768x1536 bf16
static constexpr size_t OFF_QCAT   = 3641408;    // 768x12x96 bf16
static constexpr size_t OFF_KCAT   = 4083776;    // 768x12x96 bf16
static constexpr size_t OFF_RQ     = 4526144;    // 12x768 f32
static constexpr size_t OFF_RK     = 4535360;    // 12x768 f32
static constexpr size_t OFF_VCATT  = 4986944;    // 12x96x768 bf16
static constexpr size_t OFF_BB     = 5429312;    // 12x768x768 bf16
static constexpr size_t OFF_PZT    = 8968256;    // 768x32x768 bf16
static constexpr size_t OFF_ABF    = 18405440;   // 12x768x768 bf16
static constexpr size_t OFF_OPTRAW = 21944384;   // 768x288 f32
static constexpr size_t OFF_RESF   = 22165568;   // 768x1536 bf16
static constexpr size_t OFF_ATOMF  = 22755392;   // 768x1280 bf16 (1248 used)

// ================= prep0: detect + wcat + all weight converts =================
__device__ void transpose_cv(const float* __restrict__ src, unsigned short* __restrict__ dst,
                             int K, int Kp, int N, int ky, int nx) {
  __shared__ float tl[32][33];
  const int k0 = ky * 32, n0 = nx * 32;
  const int tx = threadIdx.x & 31, ty = threadIdx.x >> 5;
  for (int it = 0; it < 4; ++it) {
    int r = ty + it * 8;
    float v = 0.f;
    if (k0 + r < K && n0 + tx < N) v = src[(long long)(k0 + r) * N + n0 + tx];
    tl[r][tx] = v;
  }
  __syncthreads();
  for (int it = 0; it < 4; ++it) {
    int r = ty + it * 8;
    if (n0 + r < N && k0 + tx < Kp)
      dst[(long long)(n0 + r) * Kp + k0 + tx] = f2bf(tl[tx][r]);
  }
}

__global__ __launch_bounds__(256) void prep0(
    float* wsf, const float* s, const float* wq, const float* wkv,
    const float* wqp, const float* wkvp, const float* tfnq_ws,
    const float* tfnkv_ws, const float* wout, const float* tfno_ws,
    const float* wb, const float* wdz, const float* bb, const float* bdz,
    const unsigned int* isa_raw)
{
  const int bx = blockIdx.x, t = threadIdx.x;
  if (bx < 288)       { int g = bx;        transpose_cv(wq,      (unsigned short*)(wsf+OFF_WQT),    384, 384, 768,  g/24, g%24); return; }
  else if (bx < 864)  { int g = bx-288;    transpose_cv(wkv,     (unsigned short*)(wsf+OFF_WKVT),   384, 384, 1536, g/48, g%48); return; }
  else if (bx < 924)  { int g = bx-864;    transpose_cv(wqp,     (unsigned short*)(wsf+OFF_WQPT),   384, 384, 144,  g/5,  g%5);  return; }
  else if (bx < 1092) { int g = bx-924;    transpose_cv(wkvp,    (unsigned short*)(wsf+OFF_WKVPT),  384, 384, 432,  g/14, g%14); return; }
  else if (bx < 1284) { int g = bx-1092;   transpose_cv(tfnq_ws, (unsigned short*)(wsf+OFF_TFNQT),  192, 256, 768,  g/24, g%24); return; }
  else if (bx < 1668) { int g = bx-1284;   transpose_cv(tfnkv_ws,(unsigned short*)(wsf+OFF_TFNKVT), 192, 256, 1536, g/48, g%48); return; }
  else if (bx < 2244) { int g = bx-1668;   transpose_cv(wout,    (unsigned short*)(wsf+OFF_WOUTT),  1536,1536,384,  g/12, g%12); return; }
  else if (bx < 2484) { int g = bx-2244;   transpose_cv(tfno_ws, (unsigned short*)(wsf+OFF_TFNOT),  1248,1280,192,  g/6,  g%6);  return; }
  else if (bx < 2772) {
    long long base = (long long)(bx - 2484) * 1024 + t * 4;
    float4 v = *(const float4*)(s + base);
    unsigned short tmp[4] = {f2bf(v.x), f2bf(v.y), f2bf(v.z), f2bf(v.w)};
    *(uint2*)((unsigned short*)(wsf + OFF_SBF) + base) = *(uint2*)tmp;
    return;
  } else if (bx < 2773) {
    __shared__ int notint, notfloat;
    int* ISA = (int*)(wsf + OFF_ISA);
    if (t == 0) { notint = 0; notfloat = 0; }
    __syncthreads();
    if (t < 192) {
      unsigned v = isa_raw[t];
      if (v > 1u) atomicOr(&notint, 1);
      if (v != 0u && v != 0x3F800000u) atomicOr(&notfloat, 1);
    }
    __syncthreads();
    const int mode = (!notint) ? 0 : ((!notfloat) ? 1 : 2);
    for (int n = t; n < NN; n += 256) {
      int val;
      if (mode == 2) val = (((const unsigned char*)isa_raw)[n] != 0);
      else           val = (isa_raw[n] != 0u);
      ISA[n] = val;
    }
    return;
  } else {
    const float rs3 = 0.57735026918962576f;
    unsigned short* WCT = (unsigned short*)(wsf + OFF_WCT);
    float* bcat = wsf + OFF_BCAT;
    int idx = (bx - 2773) * 256 + t;
    if (idx < 48 * 128) {
      int o = idx >> 7, k = idx & 127;
      float v = 0.f;
      if (o < 12) v = rs3 * wb[k * 12 + o];
      else if (o < 44) v = wdz[k * 32 + (o - 12)];
      WCT[o * 128 + k] = f2bf(v);
    }
    if (bx == 2773 && t < 48)
      bcat[t] = (t < 12) ? rs3 * bb[t] : (t < 44 ? bdz[t - 12] : 0.f);
  }
}

// ================= gemm16: 16 rows x 64 cols, 4-wave split-K =================
__device__ __forceinline__ void gemm16(
    char* lds, const unsigned short* __restrict__ A, int lda,
    const unsigned short* __restrict__ BT, int ldb, int KQ,
    const float* __restrict__ bias, int mode,
    float* Cf, unsigned short* Cb, int ldc, int Nc, int colb, int row0,
    const int* __restrict__ ISA, float* outp)
{
  v4f (*PS)[4][64] = (v4f (*)[4][64])lds;
  const int t = threadIdx.x, w = t >> 6, l = t & 63, l15 = l & 15, lg = l >> 4;
  const int rowA = row0 + l15;
  v4f acc[4] = {};
  const unsigned short* ap = A + (long long)rowA * lda + lg * 8;
  const int kend = (w + 1) * KQ;
  for (int k0 = w * KQ; k0 < kend; k0 += 32) {
    v8bf av = *(const v8bf*)(ap + k0);
#pragma unroll
    for (int cf = 0; cf < 4; ++cf) {
      v8bf bv = *(const v8bf*)(BT + (long long)(colb + cf * 16 + l15) * ldb + k0 + lg * 8);
      acc[cf] = __builtin_amdgcn_mfma_f32_16x16x32_bf16(av, bv, acc[cf], 0, 0, 0);
    }
  }
#pragma unroll
  for (int cf = 0; cf < 4; ++cf) PS[w][cf][l] = acc[cf];
  __syncthreads();
  const int cf = w;
  v4f sv = PS[0][cf][l] + PS[1][cf][l] + PS[2][cf][l] + PS[3][cf][l];
  const int c = colb + cf * 16 + l15;
  if (c < Nc) {
    float bvs = bias ? bias[c] : 0.f;
#pragma unroll
    for (int i = 0; i < 4; ++i) {
      int r = row0 + lg * 4 + i;
      float v = sv[i] + bvs;
      if (mode == 0)      Cf[(long long)r * ldc + c] = v;
      else if (mode == 1) Cb[(long long)r * ldc + c] = f2bf(v);
      else if (mode == 2) { if (!ISA[r]) outp[r * 384 + c] = v; }
      else                { if ( ISA[r]) outp[r * 384 + c] = v; }
    }
  }
}

// ================= mega1: zpass direct-reg (4608) || projection GEMMs (3936) =========
__global__ __launch_bounds__(256) void mega1(
    float* wsf, const float* __restrict__ z,
    const float* bq, const float* bkv, const float* bqp, const float* bkvp)
{
  __shared__ __align__(16) char lds[23296];
  const int t = threadIdx.x;
  if (blockIdx.x < 4608) {
    float* Sout = (float*)lds;
    const unsigned short* WCT = (const unsigned short*)(wsf + OFF_WCT);
    const float* bcat = wsf + OFF_BCAT;
    unsigned short* Bb  = (unsigned short*)(wsf + OFF_BB);
    unsigned short* PZT = (unsigned short*)(wsf + OFF_PZT);
    const long long row0 = (long long)blockIdx.x * 128;
    const int w = t >> 6, l = t & 63, l15 = l & 15, lg = l >> 4;
    v8bf bvv[4][3];
#pragma unroll
    for (int ks = 0; ks < 4; ++ks)
#pragma unroll
      for (int cf = 0; cf < 3; ++cf)
        bvv[ks][cf] = *(const v8bf*)(WCT + (cf * 16 + l15) * 128 + ks * 32 + lg * 8);
    v4f acc[2][3] = {};
#pragma unroll
    for (int rf = 0; rf < 2; ++rf) {
      const float* zrow = z + (row0 + w * 32 + rf * 16 + l15) * 128 + lg * 8;
#pragma unroll
      for (int ks = 0; ks < 4; ++ks) {
        float4 a0 = *(const float4*)(zrow + ks * 32);
        float4 a1 = *(const float4*)(zrow + ks * 32 + 4);
        unsigned short tmp[8] = {f2bf(a0.x), f2bf(a0.y), f2bf(a0.z), f2bf(a0.w),
                                 f2bf(a1.x), f2bf(a1.y), f2bf(a1.z), f2bf(a1.w)};
        v8bf av = *(const v8bf*)tmp;
#pragma unroll
        for (int cf = 0; cf < 3; ++cf)
          acc[rf][cf] = __builtin_amdgcn_mfma_f32_16x16x32_bf16(av, bvv[ks][cf], acc[rf][cf], 0, 0, 0);
      }
    }
#pragma unroll
    for (int rf = 0; rf < 2; ++rf)
#pragma unroll
      for (int cf = 0; cf < 3; ++cf) {
        int o = cf * 16 + l15;
#pragma unroll
        for (int i = 0; i < 4; ++i) {
          int m = w * 32 + rf * 16 + lg * 4 + i;
          Sout[o * 132 + m] = acc[rf][cf][i];
        }
      }
    __syncthreads();
    const int n = blockIdx.x / 6;
    const int m0 = (blockIdx.x % 6) * 128;
    for (int idx = t; idx < 44 * 8; idx += 256) {
      int o = idx >> 3, seg = idx & 7;
      float bias = bcat[o];
      unsigned short tmp[16];
#pragma unroll
      for (int j = 0; j < 16; ++j) tmp[j] = f2bf(Sout[o * 132 + seg * 16 + j] + bias);
      unsigned short* gp;
      if (o < 12) gp = Bb + ((long long)o * 768 + n) * 768 + m0 + seg * 16;
      else        gp = PZT + ((long long)n * 32 + (o - 12)) * 768 + m0 + seg * 16;
      *(uint4*)gp = *(uint4*)tmp;
      *(uint4*)(gp + 8) = *(uint4*)(tmp + 8);
    }
    return;
  }
  // ---- projection GEMMs ----
  const int g = blockIdx.x - 4608;
  const int bt = g / 82, xt = g % 82;
  const unsigned short* SBF = (const unsigned short*)(wsf + OFF_SBF);
  const unsigned short* BT; const float* bias; int ldb, KQ, mode, ldc, Nc, colb;
  float* Cf = nullptr; unsigned short* Cb = nullptr;
  if (xt < 12)      { BT=(const unsigned short*)(wsf+OFF_WQT);    bias=bq;     ldb=384; KQ=96; Cb=(unsigned short*)(wsf+OFF_QR);  ldc=768;  Nc=768;  colb=xt*64;      mode=1; }
  else if (xt < 36) { BT=(const unsigned short*)(wsf+OFF_WKVT);   bias=bkv;    ldb=384; KQ=96; Cb=(unsigned short*)(wsf+OFF_KVR); ldc=1536; Nc=1536; colb=(xt-12)*64; mode=1; }
  else if (xt < 39) { BT=(const unsigned short*)(wsf+OFF_WQPT);   bias=bqp;    ldb=384; KQ=96; Cf=wsf+OFF_QP;                     ldc=144;  Nc=144;  colb=(xt-36)*64; mode=0; }
  else if (xt < 46) { BT=(const unsigned short*)(wsf+OFF_WKVPT);  bias=bkvp;   ldb=384; KQ=96; Cf=wsf+OFF_KVP;                    ldc=432;  Nc=432;  colb=(xt-39)*64; mode=0; }
  else if (xt < 58) { BT=(const unsigned short*)(wsf+OFF_TFNQT);  bias=nullptr;ldb=256; KQ=64; Cb=(unsigned short*)(wsf+OFF_QA);  ldc=768;  Nc=768;  colb=(xt-46)*64; mode=1; }
  else              { BT=(const unsigned short*)(wsf+OFF_TFNKVT); bias=nullptr;ldb=256; KQ=64; Cb=(unsigned short*)(wsf+OFF_KVA); ldc=1536; Nc=1536; colb=(xt-58)*64; mode=1; }
  gemm16(lds, SBF, 384, BT, ldb, KQ, bias, mode, Cf, Cb, ldc, Nc, colb, bt * 16, nullptr, nullptr);
}

// ================= prep_qkv (writes VcatT transposed directly) =================
__global__ __launch_bounds__(256) void prep_qkv(
    float* wsf, const float* __restrict__ s,
    const float* __restrict__ rot, const float* __restrict__ trans,
    const float* __restrict__ head_w,
    const float* __restrict__ tfnq_wv, const float* __restrict__ tfnkv_wv)
{
  const int n = blockIdx.x, t = threadIdx.x;
  const int* ISA = (const int*)(wsf + OFF_ISA);
  const unsigned short* QRb  = (const unsigned short*)(wsf + OFF_QR);
  const unsigned short* KVRb = (const unsigned short*)(wsf + OFF_KVR);
  const unsigned short* QAb  = (const unsigned short*)(wsf + OFF_QA);
  const unsigned short* KVAb = (const unsigned short*)(wsf + OFF_KVA);
  const float* QP  = wsf + OFF_QP;
  const float* KVP = wsf + OFF_KVP;
  unsigned short* Qcat = (unsigned short*)(wsf + OFF_QCAT);
  unsigned short* Kcat = (unsigned short*)(wsf + OFF_KCAT);
  unsigned short* Vt   = (unsigned short*)(wsf + OFF_VCATT);
  float* rq = wsf + OFF_RQ;
  float* rk = wsf + OFF_RK;
  const bool isa = ISA[n] != 0;
  __shared__ float R[9], T[3], shw[12], sv[192];
  __shared__ float qs[768], ks[768], vs[768], qp[144], kp[144], vp[288];
  if (t < 9) R[t] = rot[n * 9 + t];
  if (t < 3) T[t] = trans[n * 3 + t];
  if (t >= 16 && t < 28)
    shw[t - 16] = log1pf(__expf(head_w[t - 16])) * 0.13608276348795434f;
  if (isa && t >= 32 && t < 224) sv[t - 32] = s[(size_t)n * 384 + 192 + (t - 32)];
  __syncthreads();
  for (int idx = t; idx < 768; idx += 256) {
    int h = idx >> 6, c = idx & 63;
    qs[idx] = bf2f(isa ? QAb[(long long)n * 768 + idx] : QRb[(long long)n * 768 + idx]);
    ks[idx] = bf2f(isa ? KVAb[(long long)n * 1536 + h * 128 + c] : KVRb[(long long)n * 1536 + h * 128 + c]);
    vs[idx] = bf2f(isa ? KVAb[(long long)n * 1536 + h * 128 + 64 + c] : KVRb[(long long)n * 1536 + h * 128 + 64 + c]);
  }
  if (isa) {
    for (int idx = t; idx < 144; idx += 256) {
      int hp = idx / 3, x = idx % 3;
      float a = 0.f;
      for (int i = 0; i < 64; ++i) a += sv[i * 3 + x] * tfnq_wv[i * 48 + hp];
      qp[idx] = a + T[x];
    }
    for (int idx = t; idx < 432; idx += 256) {
      int o = idx / 3, x = idx % 3;
      float a = 0.f;
      for (int i = 0; i < 64; ++i) a += sv[i * 3 + x] * tfnkv_wv[i * 144 + o];
      float v = a + T[x];
      int h = o / 12, pp = o % 12;
      if (pp < 4) kp[(h * 4 + pp) * 3 + x] = v;
      else        vp[(h * 8 + (pp - 4)) * 3 + x] = v;
    }
  } else {
    for (int idx = t; idx < 144; idx += 256) {
      int hp = idx / 3, i = idx % 3;
      qp[idx] = R[i * 3 + 0] * QP[(long long)n * 144 + 0 + hp] +
                R[i * 3 + 1] * QP[(long long)n * 144 + 48 + hp] +
                R[i * 3 + 2] * QP[(long long)n * 144 + 96 + hp] + T[i];
    }
    for (int idx = t; idx < 432; idx += 256) {
      int hp = idx / 3, i = idx % 3;
      float v = R[i * 3 + 0] * KVP[(long long)n * 432 + 0 + hp] +
                R[i * 3 + 1] * KVP[(long long)n * 432 + 144 + hp] +
                R[i * 3 + 2] * KVP[(long long)n * 432 + 288 + hp] + T[i];
      int h = hp / 12, pp = hp % 12;
      if (pp < 4) kp[(h * 4 + pp) * 3 + i] = v;
      else        vp[(h * 8 + (pp - 4)) * 3 + i] = v;
    }
  }
  __syncthreads();
  const float sq = 0.07216878364870322f;  // sqrt(1/192)
  for (int idx = t; idx < 1152; idx += 256) {
    int h = idx / 96, c = idx % 96;
    float qv = (c < 64) ? sq * qs[h * 64 + c] : ((c < 76) ? shw[h] * qp[h * 12 + (c - 64)] : 0.f);
    float kv = (c < 64) ? ks[h * 64 + c]      : ((c < 76) ? kp[h * 12 + (c - 64)] : 0.f);
    float vv = (c < 64) ? vs[h * 64 + c]      : ((c < 88) ? vp[h * 24 + (c - 64)] : 0.f);
    long long base = ((long long)n * 12 + h) * 96 + c;
    Qcat[base] = f2bf(qv);
    Kcat[base] = f2bf(kv);
    Vt[((long long)h * 96 + c) * 768 + n] = f2bf(vv);   // transposed write (L2-resident)
  }
  if (t < 24) {
    int h = t >> 1, which = t & 1;
    const float* p = which ? kp : qp;
    float s2 = 0.f;
#pragma unroll
    for (int d = 0; d < 12; ++d) { float x = p[h * 12 + d]; s2 += x * x; }
    float val = 0.5f * shw[h] * s2;
    if (which) rk[h * 768 + n] = val;
    else       rq[h * 768 + n] = val;
  }
}

// ================= mega2: logits + softmax + A-write + fused A@Vcat =================
__global__ __launch_bounds__(256) void mega2(float* wsf, const float* __restrict__ mask) {
  __shared__ __align__(16) char lds[26112];
  const int t = threadIdx.x;
  const unsigned short* Qcat = (const unsigned short*)(wsf + OFF_QCAT);
  const unsigned short* Kcat = (const unsigned short*)(wsf + OFF_KCAT);
  const unsigned short* Bb   = (const unsigned short*)(wsf + OFF_BB);
  const unsigned short* VcatT= (const unsigned short*)(wsf + OFF_VCATT);
  const float* rq = wsf + OFF_RQ;
  const float* rk = wsf + OFF_RK;
  unsigned short* Abf   = (unsigned short*)(wsf + OFF_ABF);
  unsigned short* RESF  = (unsigned short*)(wsf + OFF_RESF);
  unsigned short* ATOMF = (unsigned short*)(wsf + OFF_ATOMF);
  float* OPTRAW = wsf + OFF_OPTRAW;
  const int h = blockIdx.x / 48, r0 = (blockIdx.x % 48) * 16;
  const int w = t >> 6, l = t & 63, l15 = l & 15, lg = l >> 4;
  unsigned short* SW = (unsigned short*)lds + w * 3200;   // [16][200] per wave
  float* redm = (float*)(lds + 25600);
  float* reds = (float*)(lds + 25856);
  const int nrow = r0 + l15;
  v8bf aq[3];
#pragma unroll
  for (int ks = 0; ks < 3; ++ks)
    aq[ks] = *(const v8bf*)(Qcat + ((long long)nrow * 12 + h) * 96 + ks * 32 + lg * 8);
  v4f acc[12] = {};
#pragma unroll
  for (int cf = 0; cf < 12; ++cf) {
    int m = w * 192 + cf * 16 + l15;
    const unsigned short* kb = Kcat + ((long long)m * 12 + h) * 96 + lg * 8;
#pragma unroll
    for (int ks = 0; ks < 3; ++ks) {
      v8bf bv = *(const v8bf*)(kb + ks * 32);
      acc[cf] = __builtin_amdgcn_mfma_f32_16x16x32_bf16(aq[ks], bv, acc[cf], 0, 0, 0);
    }
  }
#pragma unroll
  for (int it = 0; it < 6; ++it) {
    int chunk = it * 64 + l;
    int row = chunk / 24, cc = (chunk % 24) * 8;
    *(uint4*)(SW + row * 200 + cc) =
        *(const uint4*)(Bb + ((long long)(h * 768 + r0 + row)) * 768 + w * 192 + cc);
  }
  __syncthreads();
  float rkm[12], mkm[12];
#pragma unroll
  for (int cf = 0; cf < 12; ++cf) {
    int m = w * 192 + cf * 16 + l15;
    rkm[cf] = rk[h * 768 + m];
    mkm[cf] = mask[m];
  }
  float rqn[4], mkn[4], mymax[4];
#pragma unroll
  for (int i = 0; i < 4; ++i) {
    int gn = r0 + lg * 4 + i;
    rqn[i] = rq[h * 768 + gn];
    mkn[i] = mask[gn];
    mymax[i] = -3.0e38f;
  }
#pragma unroll
  for (int cf = 0; cf < 12; ++cf)
#pragma unroll
    for (int i = 0; i < 4; ++i) {
      float v = acc[cf][i] + bf2f(SW[(lg * 4 + i) * 200 + cf * 16 + l15])
              - rqn[i] - rkm[cf] + 100000.0f * (mkn[i] * mkm[cf] - 1.0f);
      acc[cf][i] = v;
      mymax[i] = fmaxf(mymax[i], v);
    }
#pragma unroll
  for (int off = 1; off < 16; off <<= 1)
#pragma unroll
    for (int i = 0; i < 4; ++i) mymax[i] = fmaxf(mymax[i], __shfl_xor(mymax[i], off, 64));
  if (l15 == 0) {
#pragma unroll
    for (int i = 0; i < 4; ++i) redm[w * 16 + lg * 4 + i] = mymax[i];
  }
  __syncthreads();
  float mx[4], mysum[4];
#pragma unroll
  for (int i = 0; i < 4; ++i) {
    int rl = lg * 4 + i;
    mx[i] = fmaxf(fmaxf(redm[rl], redm[16 + rl]), fmaxf(redm[32 + rl], redm[48 + rl]));
    mysum[i] = 0.f;
  }
#pragma unroll
  for (int cf = 0; cf < 12; ++cf)
#pragma unroll
    for (int i = 0; i < 4; ++i) {
      float e = __expf(acc[cf][i] - mx[i]);
      acc[cf][i] = e;
      mysum[i] += e;
    }
#pragma unroll
  for (int off = 1; off < 16; off <<= 1)
#pragma unroll
    for (int i = 0; i < 4; ++i) mysum[i] += __shfl_xor(mysum[i], off, 64);
  if (l15 == 0) {
#pragma unroll
    for (int i = 0; i < 4; ++i) reds[w * 16 + lg * 4 + i] = mysum[i];
  }
  __syncthreads();
  float inv[4];
#pragma unroll
  for (int i = 0; i < 4; ++i) {
    int rl = lg * 4 + i;
    inv[i] = 1.0f / (reds[rl] + reds[16 + rl] + reds[32 + rl] + reds[48 + rl]);
  }
#pragma unroll
  for (int cf = 0; cf < 12; ++cf)
#pragma unroll
    for (int i = 0; i < 4; ++i)
      SW[(lg * 4 + i) * 200 + cf * 16 + l15] = f2bf(acc[cf][i] * inv[i]);
  __syncthreads();
  // write A (bf16) for attn_pair
#pragma unroll
  for (int it = 0; it < 6; ++it) {
    int chunk = it * 64 + l;
    int row = chunk / 24, cc = (chunk % 24) * 8;
    *(uint4*)(Abf + ((long long)(h * 768 + r0 + row)) * 768 + w * 192 + cc) =
        *(const uint4*)(SW + row * 200 + cc);
  }
  // ---- fused A@Vcat (split-K: wave w owns k in [w*192, w*192+192)) ----
  const unsigned short* vbase = VcatT + (long long)h * 96 * 768 + w * 192 + lg * 8;
  v4f acc2[6] = {};
  for (int kk = 0; kk < 192; kk += 32) {
    v8bf av = *(const v8bf*)(SW + l15 * 200 + kk + lg * 8);
#pragma unroll
    for (int cf = 0; cf < 6; ++cf) {
      v8bf bv = *(const v8bf*)(vbase + (long long)(cf * 16 + l15) * 768 + kk);
      acc2[cf] = __builtin_amdgcn_mfma_f32_16x16x32_bf16(av, bv, acc2[cf], 0, 0, 0);
    }
  }
  __syncthreads();
  v4f (*PS)[64] = (v4f (*)[64])lds;    // overlays SW (done with it)
#pragma unroll
  for (int cf = 0; cf < 6; ++cf) PS[w * 6 + cf][l] = acc2[cf];
  __syncthreads();
  for (int cf = w; cf < 6; cf += 4) {
    v4f sv = PS[cf][l] + PS[6 + cf][l] + PS[12 + cf][l] + PS[18 + cf][l];
    int c = cf * 16 + l15;
    int rb = r0 + lg * 4;
#pragma unroll
    for (int i = 0; i < 4; ++i) {
      int n = rb + i;
      float v = sv[i];
      if (c < 64) {
        unsigned short b = f2bf(v);
        RESF[(long long)n * 1536 + h * 64 + c] = b;
        ATOMF[(long long)n * 1280 + h * 64 + c] = b;
      } else if (c < 88) {
        OPTRAW[(long long)n * 288 + h * 24 + (c - 64)] = v;
      }
    }
  }
}

// ================= mega3: attn_pair (768) || finalize (768) =================
__global__ __launch_bounds__(256) void mega3(
    float* wsf, const float* __restrict__ rot, const float* __restrict__ trans,
    const float* __restrict__ tfno_wv, float* __restrict__ out)
{
  const int t = threadIdx.x;
  unsigned short* RESF  = (unsigned short*)(wsf + OFF_RESF);
  unsigned short* ATOMF = (unsigned short*)(wsf + OFF_ATOMF);
  if (blockIdx.x < 768) {
    __shared__ __align__(16) v4f PS[8][64];
    const unsigned short* Abf = (const unsigned short*)(wsf + OFF_ABF);
    const unsigned short* PZT = (const unsigned short*)(wsf + OFF_PZT);
    const int w = t >> 6, l = t & 63, l15 = l & 15, lg = l >> 4;
    const int n = blockIdx.x;
    const int hh = (l15 < 12) ? l15 : 0;
    const unsigned short* arow = Abf + ((long long)hh * 768 + n) * 768 + lg * 8;
    const unsigned short* pz = PZT + (long long)n * 32 * 768 + lg * 8;
    v4f acc[2] = {};
    for (int k0 = w * 192; k0 < w * 192 + 192; k0 += 32) {
      v8bf av = *(const v8bf*)(arow + k0);
#pragma unroll
      for (int cf = 0; cf < 2; ++cf) {
        v8bf bv = *(const v8bf*)(pz + (long long)(cf * 16 + l15) * 768 + k0);
        acc[cf] = __builtin_amdgcn_mfma_f32_16x16x32_bf16(av, bv, acc[cf], 0, 0, 0);
      }
    }
    PS[w * 2 + 0][l] = acc[0];
    PS[w * 2 + 1][l] = acc[1];
    __syncthreads();
    if (t < 128) {
      int cf = t >> 6, ll = t & 63;
      v4f sv = PS[cf][ll] + PS[2 + cf][ll] + PS[4 + cf][ll] + PS[6 + cf][ll];
      int zc = cf * 16 + (ll & 15);
#pragma unroll
      for (int i = 0; i < 4; ++i) {
        int hd = (ll >> 4) * 4 + i;
        if (hd < 12) {
          unsigned short b = f2bf(sv[i]);
          RESF[(long long)n * 1536 + 1152 + hd * 32 + zc] = b;
          ATOMF[(long long)n * 1280 + 864 + hd * 32 + zc] = b;
        }
      }
    }
    return;
  }
  // ---- finalize ----
  {
    const int n = blockIdx.x - 768;
    const float* OPTRAW = wsf + OFF_OPTRAW;
    const int* ISA = (const int*)(wsf + OFF_ISA);
    const bool isa = ISA[n] != 0;
    __shared__ float R[9], T[3], opt2[96][3], norml[96];
    if (t < 9) R[t] = rot[(size_t)n * 9 + t];
    if (t < 3) T[t] = trans[(size_t)n * 3 + t];
    __syncthreads();
    for (int idx = t; idx < 288; idx += 256) {
      int hp = idx / 3, i = idx % 3;
      float x = OPTRAW[(size_t)n * 288 + hp * 3 + 0] - T[0];
      float y = OPTRAW[(size_t)n * 288 + hp * 3 + 1] - T[1];
      float z = OPTRAW[(size_t)n * 288 + hp * 3 + 2] - T[2];
      opt2[hp][i] = R[0 + i] * x + R[3 + i] * y + R[6 + i] * z;  // rot^T
    }
    __syncthreads();
    if (t < 96)
      norml[t] = sqrtf(opt2[t][0] * opt2[t][0] + opt2[t][1] * opt2[t][1] +
                       opt2[t][2] * opt2[t][2] + 1e-8f);
    __syncthreads();
    const long long rb = (long long)n * 1536;
    const long long ab = (long long)n * 1280;
    for (int idx = t; idx < 288; idx += 256) {
      int x = idx / 96, hp = idx % 96;
      RESF[rb + 768 + idx] = f2bf(opt2[hp][x]);
    }
    for (int idx = t; idx < 96; idx += 256) {
      unsigned short b = f2bf(norml[idx]);
      RESF[rb + 1056 + idx] = b;
      ATOMF[ab + 768 + idx] = b;
    }
    if (isa) {
      for (int idx = t; idx < 192; idx += 256) {
        int o = idx / 3, x = idx % 3;
        float a = 0.f;
        for (int p = 0; p < 96; ++p) a += opt2[p][x] * tfno_wv[p * 64 + o];
        out[(size_t)n * 384 + 192 + idx] = a;
      }
    }
  }
}

// ================= out GEMMs (predicated writes into d_out) =================
__global__ __launch_bounds__(256) void outg(float* wsf, const float* __restrict__ bout,
                                            float* __restrict__ out) {
  __shared__ __align__(16) char lds[16384];
  const int g = blockIdx.x;
  const int bt = g / 9, xt = g % 9;
  const int* ISA = (const int*)(wsf + OFF_ISA);
  if (xt < 6)
    gemm16(lds, (const unsigned short*)(wsf + OFF_RESF), 1536,
           (const unsigned short*)(wsf + OFF_WOUTT), 1536, 384, bout, 2,
           nullptr, nullptr, 0, 384, xt * 64, bt * 16, ISA, out);
  else
    gemm16(lds, (const unsigned short*)(wsf + OFF_ATOMF), 1280,
           (const unsigned short*)(wsf + OFF_TFNOT), 1280, 320, nullptr, 3,
           nullptr, nullptr, 0, 192, (xt - 6) * 64, bt * 16, ISA, out);
}

extern "C" void kernel_launch(void* const* d_in, const int* in_sizes, int n_in,
                              void* d_out, int out_size, void* d_ws, size_t ws_size,
                              hipStream_t stream) {
  (void)in_sizes; (void)n_in; (void)out_size; (void)ws_size;
  const float* s      = (const float*)d_in[0];
  const float* z      = (const float*)d_in[1];
  const float* rot    = (const float*)d_in[2];
  const float* trans  = (const float*)d_in[3];
  const float* mask   = (const float*)d_in[4];
  const float* wq     = (const float*)d_in[6];
  const float* bq     = (const float*)d_in[7];
  const float* wkv    = (const float*)d_in[8];
  const float* bkv    = (const float*)d_in[9];
  const float* wqp    = (const float*)d_in[10];
  const float* bqp    = (const float*)d_in[11];
  const float* wkvp   = (const float*)d_in[12];
  const float* bkvp   = (const float*)d_in[13];
  const float* wb     = (const float*)d_in[14];
  const float* bb     = (const float*)d_in[15];
  const float* wdz    = (const float*)d_in[16];
  const float* bdz    = (const float*)d_in[17];
  const float* head_w = (const float*)d_in[18];
  const float* wout   = (const float*)d_in[19];
  const float* bout   = (const float*)d_in[20];
  const float* tfnq_ws  = (const float*)d_in[21];
  const float* tfnq_wv  = (const float*)d_in[22];
  const float* tfnkv_ws = (const float*)d_in[23];
  const float* tfnkv_wv = (const float*)d_in[24];
  const float* tfno_ws  = (const float*)d_in[25];
  const float* tfno_wv  = (const float*)d_in[26];

  float* wsf = (float*)d_ws;

  prep0<<<2797, 256, 0, stream>>>(wsf, s, wq, wkv, wqp, wkvp, tfnq_ws, tfnkv_ws,
                                  wout, tfno_ws, wb, wdz, bb, bdz,
                                  (const unsigned int*)d_in[5]);
  mega1<<<8544, 256, 0, stream>>>(wsf, z, bq, bkv, bqp, bkvp);
  prep_qkv<<<768, 256, 0, stream>>>(wsf, s, rot, trans, head_w, tfnq_wv, tfnkv_wv);
  mega2<<<576, 256, 0, stream>>>(wsf, mask);
  mega3<<<1536, 256, 0, stream>>>(wsf, rot, trans, tfno_wv, (float*)d_out);
  outg<<<432, 256, 0, stream>>>(wsf, bout, (float*)d_out);
}